// Round 4
// baseline (458.131 us; speedup 1.0000x reference)
//
#include <hip/hip_runtime.h>
#include <hip/hip_bf16.h>
#include <math.h>

#define N_NODES 100000
#define N_EDGES 1600000
#define NPAIRS 25000
#define HC 64          // H*C
#define NHEADS 2
#define NLAYERS 4
#define ECLS 5
#define NBUCK 196              // ceil(N / 512); bucket = dst >> 9
#define NBLK 512               // coarse pass blocks
#define EPB (N_EDGES / NBLK)   // 3125 edges per coarse block (exact)
#define NGRP (N_NODES / 16)    // 6250 16-node groups (exact)
#define LIN0_BLOCKS 1024
#define FCAP 12288             // k_fine LDS staging capacity (avg bucket ~8163)
#define NSHARD 4               // channel shards of 16 ch (3.2 MB table each: L2-fit)

typedef __attribute__((ext_vector_type(8))) short short8;
typedef __attribute__((ext_vector_type(4))) float floatx4;
union F8 { uint4 u; short8 s; };

struct PE { int p; float wt; };

// bf16 (stored as ushort) -> f32
__device__ inline float bf_lo(unsigned int u) { return __uint_as_float(u << 16); }
__device__ inline float bf_hi(unsigned int u) { return __uint_as_float(u & 0xffff0000u); }
// f32 -> bf16 bits, round-to-nearest-even
__device__ inline unsigned short f2bf(float f) {
    unsigned int u = __float_as_uint(f);
    u += 0x7FFFu + ((u >> 16) & 1u);
    return (unsigned short)(u >> 16);
}

// ---------------- CSR P1 + layer-0 linear + escore (merged) ----------------
// hcurbS layout: [4][N][16] bf16 (channel-sharded).
__global__ void k_chist_lin0(const int* __restrict__ dst, int* __restrict__ bh,
                             const float* __restrict__ in,
                             const float* __restrict__ W,        // [4][64]
                             const float* __restrict__ asrc, const float* __restrict__ adst,
                             unsigned short* __restrict__ hcurbS,
                             float* __restrict__ ssrc, float* __restrict__ sdst,
                             const float* __restrict__ eemb, float* __restrict__ escore) {
    int tid = threadIdx.x;
    if (blockIdx.x < NBLK) {
        __shared__ int lh[NBUCK];
        int blk = blockIdx.x;
        for (int i = tid; i < NBUCK; i += 256) lh[i] = 0;
        __syncthreads();
        int s = blk * EPB;
        for (int i = tid; i < EPB; i += 256) atomicAdd(&lh[dst[s + i] >> 9], 1);
        __syncthreads();
        for (int i = tid; i < NBUCK; i += 256) bh[i * NBLK + blk] = lh[i];
        return;
    }
    if (blockIdx.x >= NBLK + LIN0_BLOCKS) {
        if (tid < NLAYERS * ECLS * NHEADS) {
            int l = tid / (ECLS * NHEADS);
            int r = tid % (ECLS * NHEADS);
            int c = r >> 1;
            int h = r & 1;
            float s = 0.f;
            const float* ev = eemb + l * ECLS * HC + c * HC + h * 32;
            const float* av = asrc + l * HC + h * 32;   // att_src base passed
            for (int k = 0; k < 32; ++k) s += ev[k] * av[k];
            escore[tid] = s;
        }
        return;
    }
    int j = tid & 63;
    int wid = ((blockIdx.x - NBLK) * 256 + tid) >> 6;
    int nwaves = LIN0_BLOCKS * 4;

    float w0 = W[0 * HC + j], w1 = W[1 * HC + j], w2 = W[2 * HC + j], w3 = W[3 * HC + j];
    int head = j >> 5;
    int c = j & 31;
    float as = asrc[head * 32 + c];
    float ad = adst[head * 32 + c];

    for (int n = wid; n < N_NODES; n += nwaves) {
        int nu = __builtin_amdgcn_readfirstlane(n);
        float4 r = *(const float4*)(in + (size_t)nu * 4);
        float acc = r.x * w0 + r.y * w1 + r.z * w2 + r.w * w3;
        hcurbS[((size_t)(j >> 4) * N_NODES + nu) * 16 + (j & 15)] = f2bf(acc);
        float ps = acc * as;
        float pd = acc * ad;
        for (int off = 16; off > 0; off >>= 1) {
            ps += __shfl_down(ps, off, 32);
            pd += __shfl_down(pd, off, 32);
        }
        if (c == 0) {
            ssrc[nu * 2 + head] = ps;
            sdst[nu * 2 + head] = pd;
        }
    }
}

// P2a: per-bucket exclusive scan of the NBLK per-block counts; raw bucket
// sums to part[]. Also zeroes out[] (LAST layer accumulates via atomics).
__global__ void k_s1(const int* __restrict__ bh, int* __restrict__ bbase,
                     int* __restrict__ part, float* __restrict__ out) {
    __shared__ int tmp[NBLK];
    int tid = threadIdx.x;
    int gtid = blockIdx.x * NBLK + tid;
    if (gtid < NPAIRS) out[gtid] = 0.f;
    int i = blockIdx.x * NBLK + tid;
    int v = bh[i];
    tmp[tid] = v;
    __syncthreads();
    for (int off = 1; off < NBLK; off <<= 1) {
        int t = (tid >= off) ? tmp[tid - off] : 0;
        __syncthreads();
        tmp[tid] += t;
        __syncthreads();
    }
    bbase[i] = tmp[tid] - v;
    if (tid == NBLK - 1) part[blockIdx.x] = tmp[NBLK - 1];
}

// P3: coarse scatter, LDS-STAGED -> coalesced global writes.
__global__ void k_cscatter(const int* __restrict__ src, const int* __restrict__ dst,
                           const int* __restrict__ attr, const int* __restrict__ bbase,
                           const int* __restrict__ part, int* __restrict__ bkt) {
    __shared__ int tmp[256];
    __shared__ int cur[NBUCK];
    __shared__ int gadj[NBUCK];
    __shared__ int stage[EPB];            // 12.5 KB
    __shared__ unsigned char stb[EPB];    // 3.1 KB
    int tid = threadIdx.x, blk = blockIdx.x;
    int pv = (tid < NBUCK) ? part[tid] : 0;
    tmp[tid] = pv;
    __syncthreads();
    for (int off = 1; off < 256; off <<= 1) {
        int t = (tid >= off) ? tmp[tid - off] : 0;
        __syncthreads();
        tmp[tid] += t;
        __syncthreads();
    }
    if (tid < NBUCK) gadj[tid] = tmp[tid] - pv;
    if (tid < NBUCK) cur[tid] = 0;
    __syncthreads();
    int s0 = blk * EPB;
    for (int i = tid; i < EPB; i += 256) atomicAdd(&cur[dst[s0 + i] >> 9], 1);
    __syncthreads();
    int v = (tid < NBUCK) ? cur[tid] : 0;
    tmp[tid] = v;
    __syncthreads();
    for (int off = 1; off < 256; off <<= 1) {
        int t = (tid >= off) ? tmp[tid - off] : 0;
        __syncthreads();
        tmp[tid] += t;
        __syncthreads();
    }
    int ex = tmp[tid] - v;
    if (tid < NBUCK) {
        cur[tid] = ex;                                         // local cursor
        gadj[tid] += bbase[tid * NBLK + blk] - ex;             // global - local
    }
    __syncthreads();
    for (int i = tid; i < EPB; i += 256) {
        int e = s0 + i;
        int d = dst[e];
        int b = d >> 9;
        int pos = atomicAdd(&cur[b], 1);
        stage[pos] = src[e] | (attr[e] << 17) | ((d & 511) << 20);
        stb[pos] = (unsigned char)b;
    }
    __syncthreads();
    for (int i = tid; i < EPB; i += 256)
        bkt[gadj[stb[i]] + i] = stage[i];
}

// P4: fine sort within each bucket, LDS-STAGED (fallback if > FCAP).
__global__ void k_fine(const int* __restrict__ part, const int* __restrict__ bkt,
                       int* __restrict__ packed, int* __restrict__ rowstart) {
    __shared__ int hist[512];
    __shared__ int cur[512];
    __shared__ int pscan[512];
    __shared__ int stage[FCAP];           // 48 KB
    int b = blockIdx.x, tid = threadIdx.x;   // 512 threads
    int pv = (tid < NBUCK) ? part[tid] : 0;
    pscan[tid] = pv;
    __syncthreads();
    for (int off = 1; off < 512; off <<= 1) {
        int t = (tid >= off) ? pscan[tid - off] : 0;
        __syncthreads();
        pscan[tid] += t;
        __syncthreads();
    }
    int base = (b == 0) ? 0 : pscan[b - 1];
    int bend = pscan[b];
    int nb = bend - base;
    hist[tid] = 0;
    __syncthreads();
    for (int i = tid; i < nb; i += 512)
        atomicAdd(&hist[(bkt[base + i] >> 20) & 0x1FF], 1);
    __syncthreads();
    int v = hist[tid];
    for (int off = 1; off < 512; off <<= 1) {
        int t = (tid >= off) ? hist[tid - off] : 0;
        __syncthreads();
        hist[tid] += t;
        __syncthreads();
    }
    int excl = hist[tid] - v;
    int node = (b << 9) + tid;
    if (node <= N_NODES) rowstart[node] = base + excl;
    cur[tid] = excl;
    __syncthreads();
    if (nb <= FCAP) {
        for (int i = tid; i < nb; i += 512) {
            int p = bkt[base + i];
            int r = atomicAdd(&cur[(p >> 20) & 0x1FF], 1);
            stage[r] = p;
        }
        __syncthreads();
        for (int i = tid; i < nb; i += 512) packed[base + i] = stage[i];
    } else {
        for (int i = tid; i < nb; i += 512) {
            int p = bkt[base + i];
            int r = atomicAdd(&cur[(p >> 20) & 0x1FF], 1);
            packed[base + r] = p;
        }
    }
}

// ---------------- MFMA linear (layers 1..3) ----------------
// Writes hcurbS in channel-sharded layout [4][N][16].
__global__ void k_linmfma(const unsigned short* __restrict__ actB,
                          const float* __restrict__ Wl,       // [64][64] fp32
                          const float* __restrict__ asrc,     // [64]
                          const float* __restrict__ adst,     // [64]
                          unsigned short* __restrict__ hcurbS,
                          float* __restrict__ ssrc, float* __restrict__ sdst) {
    __shared__ uint4 WB[512];
    __shared__ unsigned short Cb[4][1024];
    int tid = threadIdx.x;
    int lane = tid & 63;
    int w = tid >> 6;
    int q = lane >> 4;
    int c = lane & 15;

    for (int rid = tid; rid < 512; rid += 256) {
        int kk = rid >> 8;
        int t  = (rid >> 6) & 3;
        int ln = rid & 63;
        int qq = ln >> 4, cc = ln & 15;
        unsigned int u[4];
        #pragma unroll
        for (int jj = 0; jj < 4; ++jj) {
            float v0 = Wl[(kk * 32 + qq * 8 + jj * 2 + 0) * 64 + 16 * t + cc];
            float v1 = Wl[(kk * 32 + qq * 8 + jj * 2 + 1) * 64 + 16 * t + cc];
            u[jj] = (unsigned int)f2bf(v0) | ((unsigned int)f2bf(v1) << 16);
        }
        WB[rid] = make_uint4(u[0], u[1], u[2], u[3]);
    }
    __syncthreads();

    short8 bfr[2][4];
    #pragma unroll
    for (int kk = 0; kk < 2; ++kk)
        #pragma unroll
        for (int t = 0; t < 4; ++t) {
            F8 tmp; tmp.u = WB[(kk * 4 + t) * 64 + lane];
            bfr[kk][t] = tmp.s;
        }

    float as_[4], ad_[4];
    #pragma unroll
    for (int t = 0; t < 4; ++t) {
        as_[t] = asrc[16 * t + c];
        ad_[t] = adst[16 * t + c];
    }

    int wid = (blockIdx.x * 256 + tid) >> 6;
    int nwaves = gridDim.x * 4;

    for (int g = wid; g < NGRP; g += nwaves) {
        int base = g * 16;
        F8 a0, a1;
        a0.u = *(const uint4*)(actB + (size_t)(base + c) * HC + q * 8);
        a1.u = *(const uint4*)(actB + (size_t)(base + c) * HC + 32 + q * 8);

        floatx4 acc[4];
        #pragma unroll
        for (int t = 0; t < 4; ++t) {
            acc[t] = (floatx4){0.f, 0.f, 0.f, 0.f};
            acc[t] = __builtin_amdgcn_mfma_f32_16x16x32_bf16(a0.s, bfr[0][t], acc[t], 0, 0, 0);
            acc[t] = __builtin_amdgcn_mfma_f32_16x16x32_bf16(a1.s, bfr[1][t], acc[t], 0, 0, 0);
        }

        #pragma unroll
        for (int r = 0; r < 4; ++r) {
            float h0s = acc[0][r] * as_[0] + acc[1][r] * as_[1];
            float h1s = acc[2][r] * as_[2] + acc[3][r] * as_[3];
            float h0d = acc[0][r] * ad_[0] + acc[1][r] * ad_[1];
            float h1d = acc[2][r] * ad_[2] + acc[3][r] * ad_[3];
            #pragma unroll
            for (int off = 1; off < 16; off <<= 1) {
                h0s += __shfl_xor(h0s, off, 64);
                h1s += __shfl_xor(h1s, off, 64);
                h0d += __shfl_xor(h0d, off, 64);
                h1d += __shfl_xor(h1d, off, 64);
            }
            if (c == 0) {
                int node = base + q * 4 + r;
                *(float2*)(ssrc + node * 2) = make_float2(h0s, h1s);
                *(float2*)(sdst + node * 2) = make_float2(h0d, h1d);
            }
        }

        // Cb relayout: [shard t][node r16][16 ch]
        #pragma unroll
        for (int t = 0; t < 4; ++t)
            #pragma unroll
            for (int r = 0; r < 4; ++r)
                Cb[w][t * 256 + (q * 4 + r) * 16 + c] = f2bf(acc[t][r]);
        __builtin_amdgcn_wave_barrier();
        const uint4* cf = (const uint4*)&Cb[w][0];
        #pragma unroll
        for (int pass = 0; pass < 2; ++pass) {
            int s = pass * 2 + (lane >> 5);
            int idx = lane & 31;
            uint4 v = cf[s * 32 + idx];
            *(uint4*)(hcurbS + ((size_t)s * N_NODES + base) * 16 + idx * 8) = v;
        }
        __builtin_amdgcn_wave_barrier();
    }
}

// ---------------- sharded fused edge pipeline (v4) -------------------------
// 4 channel shards of 16 ch; shard table = 3.2 MB (fits one XCD L2).
// bid&7 selects XCD (round-robin dispatch); shard = (bid&7)>>1 pins each
// shard's gather working set to one XCD pair's L2.
// Block: 256 threads = 128 2-lane slots; slot owns one node's 16 channels.
// Phase 1 (edge-parallel, per shard's head): wt -> ebuf {p,wt}; per-
//   (node,class) sums via LDS atomics (eemb factoring; ssum free).
// Phase 2: slot walks its edge list, 4 gathers (32 B/edge) in flight.
// LAST: 256-node spans (64 pairs); per-shard 16-ch pair-dot partials
//   accumulated into out[] with atomicAdd (out zeroed in k_s1).
template <bool LAST>
__global__ __launch_bounds__(256)
void k_edge3(const int* __restrict__ rowstart, const int* __restrict__ packed,
             const float* __restrict__ ssrc, const float* __restrict__ sdst,
             const float* __restrict__ escore_l,   // [5][2]
             const unsigned short* __restrict__ hcurbS, // [4][N][16] bf16
             const float* __restrict__ eemb_l,     // [5][64]
             const float* __restrict__ bias_l,     // [64]
             unsigned short* __restrict__ actnext, float* __restrict__ out) {
    constexpr int SPAN  = LAST ? 256 : 128;
    constexpr int CAP   = LAST ? 4608 : 2560;     // mean 4096/2048, >7 sigma
    constexpr int NSPAN = LAST ? 391 : 782;
    __shared__ float2 ebuf[CAP];                  // {p bits, wt(hh)}
    __shared__ float  cls[SPAN * ECLS];           // [node][class] wt sums (hh)
    __shared__ float  sdl[SPAN];                  // sdst[node][hh]
    __shared__ float  esc[ECLS];

    const int tid = threadIdx.x;
    const int bid = blockIdx.x;
    const int xcd = bid & 7;
    const int shard = xcd >> 1;
    const int spanIdx = (bid >> 3) * 2 + (xcd & 1);
    if (spanIdx >= NSPAN) return;
    const int hh = shard >> 1;                    // head of this shard's ch
    const int n0 = spanIdx * SPAN;
    const int nEnd = (n0 + SPAN < N_NODES) ? n0 + SPAN : N_NODES;

    for (int i = tid; i < SPAN * ECLS; i += 256) cls[i] = 0.f;
    if (tid < ECLS) esc[tid] = escore_l[tid * 2 + hh];
    for (int i = tid; i < SPAN; i += 256) {
        int nn = n0 + i; if (nn >= N_NODES) nn = N_NODES - 1;
        sdl[i] = sdst[nn * 2 + hh];
    }
    const int beg = rowstart[n0];
    const int end = rowstart[nEnd];
    __syncthreads();

    // ---- phase 1: edge-parallel wt + class sums (this shard's head) ----
    const int nb = end - beg;
    for (int i = tid; i < nb; i += 256) {
        int p = packed[beg + i];
        int dl = ((p >> 20) & 511) - (n0 & 511);
        if (!LAST || ((dl & 2) == 0)) {           // LAST: user/item only
            int s = p & 0x1FFFF;
            int a = (p >> 17) & 7;
            float lg = sdl[dl] + ssrc[s * 2 + hh] + esc[a];
            lg = lg >= 0.f ? lg : 0.2f * lg;
            float wt = __expf(lg);
            if (i < CAP) ebuf[i] = make_float2(__int_as_float(p), wt);
            atomicAdd(&cls[dl * ECLS + a], wt);
        }
    }
    __syncthreads();

    // ---- phase 2: slot-per-node (2 lanes, 8 ch each), 4-deep MLP ----
    const int lane = tid & 63;
    const int p2 = lane & 1;                      // 16B half of the 32B row
    const int slot = (tid >> 6) * 32 + (lane >> 1);   // 0..127
    int myn, gp = 0;
    bool valid;
    if (LAST) {
        gp = spanIdx * 64 + (slot >> 1);
        valid = gp < NPAIRS;
        myn = n0 + (slot >> 1) * 4 + (slot & 1);  // user 4j / item 4j+1
    } else {
        myn = n0 + slot;
        valid = myn < N_NODES;
    }
    const int b0 = valid ? rowstart[myn] : 0;
    const int b1 = valid ? rowstart[myn + 1] : 0;
    const unsigned short* hb = hcurbS + (size_t)shard * N_NODES * 16 + p2 * 8;
    const int dl = myn - n0;

    float4 a0 = make_float4(0.f, 0.f, 0.f, 0.f);
    float4 a1 = make_float4(0.f, 0.f, 0.f, 0.f);

    auto fetch = [&](int i) -> PE {
        int j = i - beg;
        if (j < CAP) {
            float2 t = ebuf[j];
            PE r; r.p = __float_as_int(t.x); r.wt = t.y; return r;
        }
        int p = packed[i];                         // overflow fallback
        int a = (p >> 17) & 7;
        int s = p & 0x1FFFF;
        float lg = sdl[dl] + ssrc[s * 2 + hh] + esc[a];
        lg = lg >= 0.f ? lg : 0.2f * lg;
        PE r; r.p = p; r.wt = __expf(lg); return r;
    };

#define ACC8(wt, hv) do { \
        a0.x += (wt) * bf_lo((hv).x); a0.y += (wt) * bf_hi((hv).x); \
        a0.z += (wt) * bf_lo((hv).y); a0.w += (wt) * bf_hi((hv).y); \
        a1.x += (wt) * bf_lo((hv).z); a1.y += (wt) * bf_hi((hv).z); \
        a1.z += (wt) * bf_lo((hv).w); a1.w += (wt) * bf_hi((hv).w); \
    } while (0)

    int i = b0;
    for (; i + 4 <= b1; i += 4) {
        PE e0 = fetch(i);
        PE e1 = fetch(i + 1);
        PE e2 = fetch(i + 2);
        PE e3 = fetch(i + 3);
        uint4 h0 = *(const uint4*)(hb + (size_t)(e0.p & 0x1FFFF) * 16);
        uint4 h1 = *(const uint4*)(hb + (size_t)(e1.p & 0x1FFFF) * 16);
        uint4 h2 = *(const uint4*)(hb + (size_t)(e2.p & 0x1FFFF) * 16);
        uint4 h3 = *(const uint4*)(hb + (size_t)(e3.p & 0x1FFFF) * 16);
        ACC8(e0.wt, h0);
        ACC8(e1.wt, h1);
        ACC8(e2.wt, h2);
        ACC8(e3.wt, h3);
    }
    for (; i < b1; ++i) {
        PE e0 = fetch(i);
        uint4 h0 = *(const uint4*)(hb + (size_t)(e0.p & 0x1FFFF) * 16);
        ACC8(e0.wt, h0);
    }
#undef ACC8

    // ---- epilogue: fold class sums, normalize, bias, elu ----
    float ssum = 0.f;
    const float* ef = eemb_l + shard * 16 + p2 * 8;
    #pragma unroll
    for (int a = 0; a < ECLS; ++a) {
        float c = cls[dl * ECLS + a];
        ssum += c;
        float4 e0 = *(const float4*)(ef + a * HC);
        float4 e1 = *(const float4*)(ef + a * HC + 4);
        a0.x += c * e0.x; a0.y += c * e0.y; a0.z += c * e0.z; a0.w += c * e0.w;
        a1.x += c * e1.x; a1.y += c * e1.y; a1.z += c * e1.z; a1.w += c * e1.w;
    }
    float inv = 1.f / (ssum + 1e-16f);
    const float* bf = bias_l + shard * 16 + p2 * 8;
    float4 bv0 = *(const float4*)(bf);
    float4 bv1 = *(const float4*)(bf + 4);
    float o0 = a0.x * inv + bv0.x; o0 = o0 > 0.f ? o0 : (__expf(o0) - 1.f);
    float o1 = a0.y * inv + bv0.y; o1 = o1 > 0.f ? o1 : (__expf(o1) - 1.f);
    float o2 = a0.z * inv + bv0.z; o2 = o2 > 0.f ? o2 : (__expf(o2) - 1.f);
    float o3 = a0.w * inv + bv0.w; o3 = o3 > 0.f ? o3 : (__expf(o3) - 1.f);
    float o4 = a1.x * inv + bv1.x; o4 = o4 > 0.f ? o4 : (__expf(o4) - 1.f);
    float o5 = a1.y * inv + bv1.y; o5 = o5 > 0.f ? o5 : (__expf(o5) - 1.f);
    float o6 = a1.z * inv + bv1.z; o6 = o6 > 0.f ? o6 : (__expf(o6) - 1.f);
    float o7 = a1.w * inv + bv1.w; o7 = o7 > 0.f ? o7 : (__expf(o7) - 1.f);

    if (!LAST) {
        if (valid) {
            unsigned int u0 = (unsigned int)f2bf(o0) | ((unsigned int)f2bf(o1) << 16);
            unsigned int u1 = (unsigned int)f2bf(o2) | ((unsigned int)f2bf(o3) << 16);
            unsigned int u2 = (unsigned int)f2bf(o4) | ((unsigned int)f2bf(o5) << 16);
            unsigned int u3 = (unsigned int)f2bf(o6) | ((unsigned int)f2bf(o7) << 16);
            *(uint4*)(actnext + (size_t)myn * HC + shard * 16 + p2 * 8) =
                make_uint4(u0, u1, u2, u3);
        }
    } else {
        // partner node's same channels live at lane^2 (slot^1);
        // lane^1 holds the other 8-ch half of the same node.
        float pd = o0 * __shfl_xor(o0, 2, 64)
                 + o1 * __shfl_xor(o1, 2, 64)
                 + o2 * __shfl_xor(o2, 2, 64)
                 + o3 * __shfl_xor(o3, 2, 64)
                 + o4 * __shfl_xor(o4, 2, 64)
                 + o5 * __shfl_xor(o5, 2, 64)
                 + o6 * __shfl_xor(o6, 2, 64)
                 + o7 * __shfl_xor(o7, 2, 64);
        pd += __shfl_xor(pd, 1, 64);
        if (valid && ((lane & 3) == 0)) atomicAdd(out + gp, pd);
    }
}

// ---------------- launch ----------------
extern "C" void kernel_launch(void* const* d_in, const int* in_sizes, int n_in,
                              void* d_out, int out_size, void* d_ws, size_t ws_size,
                              hipStream_t stream) {
    const float* x       = (const float*)d_in[0];   // [N,4]
    const float* W0      = (const float*)d_in[1];   // [4,64]
    const float* W13     = (const float*)d_in[2];   // [3,64,64]
    const float* eemb    = (const float*)d_in[3];   // [4,5,64]
    const float* att_src = (const float*)d_in[4];   // [4,2,32]
    const float* att_dst = (const float*)d_in[5];   // [4,2,32]
    const float* bias    = (const float*)d_in[6];   // [4,64]
    const int*   eidx    = (const int*)d_in[7];     // [2,E]
    const int*   eattr   = (const int*)d_in[8];     // [E]
    float* out = (float*)d_out;

    const int* src = eidx;
    const int* dst = eidx + N_EDGES;

    char* wsb = (char*)d_ws;
    size_t off = 0;
    auto alloc = [&](size_t bytes) { char* p = wsb + off; off += (bytes + 255) & ~(size_t)255; return p; };
    unsigned short* hcurbS = (unsigned short*)alloc((size_t)NSHARD * N_NODES * 16 * 2);
    unsigned short* actB   = (unsigned short*)alloc((size_t)N_NODES * HC * 2);
    float*          ssrc   = (float*)alloc((size_t)N_NODES * 2 * 4);
    float*          sdst   = (float*)alloc((size_t)N_NODES * 2 * 4);
    float*          escore = (float*)alloc(NLAYERS * ECLS * NHEADS * 4);
    int*            bh     = (int*)alloc((size_t)NBUCK * NBLK * 4);
    int*            bbase  = (int*)alloc((size_t)NBUCK * NBLK * 4);
    int*            part   = (int*)alloc(256 * 4);
    int*            rowstart = (int*)alloc(((size_t)N_NODES + 1) * 4);
    int*            bkt    = (int*)alloc((size_t)N_EDGES * 4);
    int*            packed = (int*)alloc((size_t)N_EDGES * 4);

    // ---- CSR build P1 + layer-0 linear + escore (merged) ----
    k_chist_lin0<<<NBLK + LIN0_BLOCKS + 1, 256, 0, stream>>>(
        dst, bh, x, W0, att_src, att_dst, hcurbS, ssrc, sdst, eemb, escore);
    k_s1<<<NBUCK, NBLK, 0, stream>>>(bh, bbase, part, out);
    k_cscatter<<<NBLK, 256, 0, stream>>>(src, dst, eattr, bbase, part, bkt);
    k_fine<<<NBUCK, 512, 0, stream>>>(part, bkt, packed, rowstart);

    for (int l = 0; l < NLAYERS; ++l) {
        if (l > 0) {
            k_linmfma<<<512, 256, 0, stream>>>(
                actB, W13 + (size_t)(l - 1) * HC * HC,
                att_src + l * HC, att_dst + l * HC, hcurbS, ssrc, sdst);
        }
        const float* esl = escore + l * ECLS * NHEADS;
        const float* el  = eemb + (size_t)l * ECLS * HC;
        const float* bl  = bias + l * HC;
        if (l < NLAYERS - 1)
            k_edge3<false><<<8 * 391, 256, 0, stream>>>(
                rowstart, packed, ssrc, sdst, esl, hcurbS, el, bl, actB, nullptr);
        else
            k_edge3<true><<<8 * 196, 256, 0, stream>>>(
                rowstart, packed, ssrc, sdst, esl, hcurbS, el, bl, nullptr, out);
    }
}

// Round 5
// 367.559 us; speedup vs baseline: 1.2464x; 1.2464x over previous
//
#include <hip/hip_runtime.h>
#include <hip/hip_bf16.h>
#include <math.h>

#define N_NODES 100000
#define N_EDGES 1600000
#define NPAIRS 25000
#define HC 64          // H*C
#define NHEADS 2
#define NLAYERS 4
#define ECLS 5
#define NBUCK 196              // ceil(N / 512); bucket = dst >> 9
#define NBLK 512               // coarse pass blocks
#define EPB (N_EDGES / NBLK)   // 3125 edges per coarse block (exact)
#define NGRP (N_NODES / 16)    // 6250 16-node groups (exact)
#define LIN0_BLOCKS 1024
#define FCAP 12288             // k_fine LDS staging capacity (avg bucket ~8163)

typedef __attribute__((ext_vector_type(8))) short short8;
typedef __attribute__((ext_vector_type(4))) float floatx4;
union F8 { uint4 u; short8 s; };

struct PE { int p; float wt; };

// bf16 (stored as ushort) -> f32
__device__ inline float bf_lo(unsigned int u) { return __uint_as_float(u << 16); }
__device__ inline float bf_hi(unsigned int u) { return __uint_as_float(u & 0xffff0000u); }
// f32 -> bf16 bits, round-to-nearest-even
__device__ inline unsigned short f2bf(float f) {
    unsigned int u = __float_as_uint(f);
    u += 0x7FFFu + ((u >> 16) & 1u);
    return (unsigned short)(u >> 16);
}

// ---------------- CSR P1 + layer-0 linear + escore (merged) ----------------
__global__ void k_chist_lin0(const int* __restrict__ dst, int* __restrict__ bh,
                             const float* __restrict__ in,
                             const float* __restrict__ W,        // [4][64]
                             const float* __restrict__ asrc, const float* __restrict__ adst,
                             unsigned short* __restrict__ hcurb,
                             float* __restrict__ ssrc, float* __restrict__ sdst,
                             const float* __restrict__ eemb, float* __restrict__ escore) {
    int tid = threadIdx.x;
    if (blockIdx.x < NBLK) {
        __shared__ int lh[NBUCK];
        int blk = blockIdx.x;
        for (int i = tid; i < NBUCK; i += 256) lh[i] = 0;
        __syncthreads();
        int s = blk * EPB;
        for (int i = tid; i < EPB; i += 256) atomicAdd(&lh[dst[s + i] >> 9], 1);
        __syncthreads();
        for (int i = tid; i < NBUCK; i += 256) bh[i * NBLK + blk] = lh[i];
        return;
    }
    if (blockIdx.x >= NBLK + LIN0_BLOCKS) {
        if (tid < NLAYERS * ECLS * NHEADS) {
            int l = tid / (ECLS * NHEADS);
            int r = tid % (ECLS * NHEADS);
            int c = r >> 1;
            int h = r & 1;
            float s = 0.f;
            const float* ev = eemb + l * ECLS * HC + c * HC + h * 32;
            const float* av = asrc + l * HC + h * 32;   // att_src base passed
            for (int k = 0; k < 32; ++k) s += ev[k] * av[k];
            escore[tid] = s;
        }
        return;
    }
    int j = tid & 63;
    int wid = ((blockIdx.x - NBLK) * 256 + tid) >> 6;
    int nwaves = LIN0_BLOCKS * 4;

    float w0 = W[0 * HC + j], w1 = W[1 * HC + j], w2 = W[2 * HC + j], w3 = W[3 * HC + j];
    int head = j >> 5;
    int c = j & 31;
    float as = asrc[head * 32 + c];
    float ad = adst[head * 32 + c];

    for (int n = wid; n < N_NODES; n += nwaves) {
        int nu = __builtin_amdgcn_readfirstlane(n);
        float4 r = *(const float4*)(in + (size_t)nu * 4);
        float acc = r.x * w0 + r.y * w1 + r.z * w2 + r.w * w3;
        hcurb[(size_t)nu * HC + j] = f2bf(acc);
        float ps = acc * as;
        float pd = acc * ad;
        for (int off = 16; off > 0; off >>= 1) {
            ps += __shfl_down(ps, off, 32);
            pd += __shfl_down(pd, off, 32);
        }
        if (c == 0) {
            ssrc[nu * 2 + head] = ps;
            sdst[nu * 2 + head] = pd;
        }
    }
}

// P2a: per-bucket exclusive scan of the NBLK per-block counts; raw bucket
// sums to part[].
__global__ void k_s1(const int* __restrict__ bh, int* __restrict__ bbase,
                     int* __restrict__ part) {
    __shared__ int tmp[NBLK];
    int tid = threadIdx.x;
    int i = blockIdx.x * NBLK + tid;
    int v = bh[i];
    tmp[tid] = v;
    __syncthreads();
    for (int off = 1; off < NBLK; off <<= 1) {
        int t = (tid >= off) ? tmp[tid - off] : 0;
        __syncthreads();
        tmp[tid] += t;
        __syncthreads();
    }
    bbase[i] = tmp[tid] - v;
    if (tid == NBLK - 1) part[blockIdx.x] = tmp[NBLK - 1];
}

// P3: coarse scatter, LDS-STAGED -> coalesced global writes.
__global__ void k_cscatter(const int* __restrict__ src, const int* __restrict__ dst,
                           const int* __restrict__ attr, const int* __restrict__ bbase,
                           const int* __restrict__ part, int* __restrict__ bkt) {
    __shared__ int tmp[256];
    __shared__ int cur[NBUCK];
    __shared__ int gadj[NBUCK];
    __shared__ int stage[EPB];            // 12.5 KB
    __shared__ unsigned char stb[EPB];    // 3.1 KB
    int tid = threadIdx.x, blk = blockIdx.x;
    int pv = (tid < NBUCK) ? part[tid] : 0;
    tmp[tid] = pv;
    __syncthreads();
    for (int off = 1; off < 256; off <<= 1) {
        int t = (tid >= off) ? tmp[tid - off] : 0;
        __syncthreads();
        tmp[tid] += t;
        __syncthreads();
    }
    if (tid < NBUCK) gadj[tid] = tmp[tid] - pv;
    if (tid < NBUCK) cur[tid] = 0;
    __syncthreads();
    int s0 = blk * EPB;
    for (int i = tid; i < EPB; i += 256) atomicAdd(&cur[dst[s0 + i] >> 9], 1);
    __syncthreads();
    int v = (tid < NBUCK) ? cur[tid] : 0;
    tmp[tid] = v;
    __syncthreads();
    for (int off = 1; off < 256; off <<= 1) {
        int t = (tid >= off) ? tmp[tid - off] : 0;
        __syncthreads();
        tmp[tid] += t;
        __syncthreads();
    }
    int ex = tmp[tid] - v;
    if (tid < NBUCK) {
        cur[tid] = ex;                                         // local cursor
        gadj[tid] += bbase[tid * NBLK + blk] - ex;             // global - local
    }
    __syncthreads();
    for (int i = tid; i < EPB; i += 256) {
        int e = s0 + i;
        int d = dst[e];
        int b = d >> 9;
        int pos = atomicAdd(&cur[b], 1);
        stage[pos] = src[e] | (attr[e] << 17) | ((d & 511) << 20);
        stb[pos] = (unsigned char)b;
    }
    __syncthreads();
    for (int i = tid; i < EPB; i += 256)
        bkt[gadj[stb[i]] + i] = stage[i];
}

// P4: fine sort within each bucket, LDS-STAGED (fallback if > FCAP).
__global__ void k_fine(const int* __restrict__ part, const int* __restrict__ bkt,
                       int* __restrict__ packed, int* __restrict__ rowstart) {
    __shared__ int hist[512];
    __shared__ int cur[512];
    __shared__ int pscan[512];
    __shared__ int stage[FCAP];           // 48 KB
    int b = blockIdx.x, tid = threadIdx.x;   // 512 threads
    int pv = (tid < NBUCK) ? part[tid] : 0;
    pscan[tid] = pv;
    __syncthreads();
    for (int off = 1; off < 512; off <<= 1) {
        int t = (tid >= off) ? pscan[tid - off] : 0;
        __syncthreads();
        pscan[tid] += t;
        __syncthreads();
    }
    int base = (b == 0) ? 0 : pscan[b - 1];
    int bend = pscan[b];
    int nb = bend - base;
    hist[tid] = 0;
    __syncthreads();
    for (int i = tid; i < nb; i += 512)
        atomicAdd(&hist[(bkt[base + i] >> 20) & 0x1FF], 1);
    __syncthreads();
    int v = hist[tid];
    for (int off = 1; off < 512; off <<= 1) {
        int t = (tid >= off) ? hist[tid - off] : 0;
        __syncthreads();
        hist[tid] += t;
        __syncthreads();
    }
    int excl = hist[tid] - v;
    int node = (b << 9) + tid;
    if (node <= N_NODES) rowstart[node] = base + excl;
    cur[tid] = excl;
    __syncthreads();
    if (nb <= FCAP) {
        for (int i = tid; i < nb; i += 512) {
            int p = bkt[base + i];
            int r = atomicAdd(&cur[(p >> 20) & 0x1FF], 1);
            stage[r] = p;
        }
        __syncthreads();
        for (int i = tid; i < nb; i += 512) packed[base + i] = stage[i];
    } else {
        for (int i = tid; i < nb; i += 512) {
            int p = bkt[base + i];
            int r = atomicAdd(&cur[(p >> 20) & 0x1FF], 1);
            packed[base + r] = p;
        }
    }
}

// ---------------- MFMA linear (layers 1..3) ----------------
__global__ void k_linmfma(const unsigned short* __restrict__ actB,
                          const float* __restrict__ Wl,       // [64][64] fp32
                          const float* __restrict__ asrc,     // [64]
                          const float* __restrict__ adst,     // [64]
                          unsigned short* __restrict__ hcurb,
                          float* __restrict__ ssrc, float* __restrict__ sdst) {
    __shared__ uint4 WB[512];
    __shared__ unsigned short Cb[4][1024];
    int tid = threadIdx.x;
    int lane = tid & 63;
    int w = tid >> 6;
    int q = lane >> 4;
    int c = lane & 15;

    for (int rid = tid; rid < 512; rid += 256) {
        int kk = rid >> 8;
        int t  = (rid >> 6) & 3;
        int ln = rid & 63;
        int qq = ln >> 4, cc = ln & 15;
        unsigned int u[4];
        #pragma unroll
        for (int jj = 0; jj < 4; ++jj) {
            float v0 = Wl[(kk * 32 + qq * 8 + jj * 2 + 0) * 64 + 16 * t + cc];
            float v1 = Wl[(kk * 32 + qq * 8 + jj * 2 + 1) * 64 + 16 * t + cc];
            u[jj] = (unsigned int)f2bf(v0) | ((unsigned int)f2bf(v1) << 16);
        }
        WB[rid] = make_uint4(u[0], u[1], u[2], u[3]);
    }
    __syncthreads();

    short8 bfr[2][4];
    #pragma unroll
    for (int kk = 0; kk < 2; ++kk)
        #pragma unroll
        for (int t = 0; t < 4; ++t) {
            F8 tmp; tmp.u = WB[(kk * 4 + t) * 64 + lane];
            bfr[kk][t] = tmp.s;
        }

    float as_[4], ad_[4];
    #pragma unroll
    for (int t = 0; t < 4; ++t) {
        as_[t] = asrc[16 * t + c];
        ad_[t] = adst[16 * t + c];
    }

    int wid = (blockIdx.x * 256 + tid) >> 6;
    int nwaves = gridDim.x * 4;

    for (int g = wid; g < NGRP; g += nwaves) {
        int base = g * 16;
        F8 a0, a1;
        a0.u = *(const uint4*)(actB + (size_t)(base + c) * HC + q * 8);
        a1.u = *(const uint4*)(actB + (size_t)(base + c) * HC + 32 + q * 8);

        floatx4 acc[4];
        #pragma unroll
        for (int t = 0; t < 4; ++t) {
            acc[t] = (floatx4){0.f, 0.f, 0.f, 0.f};
            acc[t] = __builtin_amdgcn_mfma_f32_16x16x32_bf16(a0.s, bfr[0][t], acc[t], 0, 0, 0);
            acc[t] = __builtin_amdgcn_mfma_f32_16x16x32_bf16(a1.s, bfr[1][t], acc[t], 0, 0, 0);
        }

        #pragma unroll
        for (int r = 0; r < 4; ++r) {
            float h0s = acc[0][r] * as_[0] + acc[1][r] * as_[1];
            float h1s = acc[2][r] * as_[2] + acc[3][r] * as_[3];
            float h0d = acc[0][r] * ad_[0] + acc[1][r] * ad_[1];
            float h1d = acc[2][r] * ad_[2] + acc[3][r] * ad_[3];
            #pragma unroll
            for (int off = 1; off < 16; off <<= 1) {
                h0s += __shfl_xor(h0s, off, 64);
                h1s += __shfl_xor(h1s, off, 64);
                h0d += __shfl_xor(h0d, off, 64);
                h1d += __shfl_xor(h1d, off, 64);
            }
            if (c == 0) {
                int node = base + q * 4 + r;
                *(float2*)(ssrc + node * 2) = make_float2(h0s, h1s);
                *(float2*)(sdst + node * 2) = make_float2(h0d, h1d);
            }
        }

        #pragma unroll
        for (int t = 0; t < 4; ++t)
            #pragma unroll
            for (int r = 0; r < 4; ++r)
                Cb[w][(q * 4 + r) * 64 + 16 * t + c] = f2bf(acc[t][r]);
        __builtin_amdgcn_wave_barrier();
        const uint4* cf = (const uint4*)&Cb[w][0];
        uint4* gout = (uint4*)(hcurb + (size_t)base * HC);
        gout[lane] = cf[lane];
        gout[64 + lane] = cf[64 + lane];
        __builtin_amdgcn_wave_barrier();
    }
}

// ---------------- fused edge pipeline (v5: big-span, batched phase 1) ------
// 512 threads, 128-node spans (782 blocks, ~3/CU, 24 waves/CU).
// Phase 1: batch-4 MLP on the dependent packed->ssrc chain; per-
//   (node,class,head) weight sums via LDS atomics (eemb factoring).
// Phase 2: 64 8-lane slots; non-LAST: 2 nodes/slot sequential; LAST:
//   slot = one pair-node, dot via shfl_xor(.,8), direct store.
template <bool LAST>
__global__ __launch_bounds__(512)
void k_edge4(const int* __restrict__ rowstart, const int* __restrict__ packed,
             const float* __restrict__ ssrc, const float* __restrict__ sdst,
             const float* __restrict__ escore_l,   // [5][2]
             const unsigned short* __restrict__ hcurb, // [N][64] bf16
             const float* __restrict__ eemb_l,     // [5][64]
             const float* __restrict__ bias_l,     // [64]
             unsigned short* __restrict__ actnext, float* __restrict__ out) {
    constexpr int SPAN = 128;
    constexpr int CAP  = 2944;            // mean 2048, ~+20 sigma
    __shared__ int   pe[CAP];             // 11.5 KB
    __shared__ float w0b[CAP];            // 11.5 KB
    __shared__ float w1b[CAP];            // 11.5 KB
    __shared__ float  cls[SPAN * 10];     // [node][class][head] wt sums
    __shared__ float2 sdl[SPAN];
    __shared__ float2 esc2[ECLS];

    const int tid = threadIdx.x;
    const int n0 = blockIdx.x * SPAN;

    for (int i = tid; i < SPAN * 10; i += 512) cls[i] = 0.f;
    if (tid < ECLS) esc2[tid] = ((const float2*)escore_l)[tid];
    if (tid < SPAN) {
        int nn = n0 + tid; if (nn > N_NODES - 1) nn = N_NODES - 1;
        sdl[tid] = ((const float2*)sdst)[nn];
    }
    int spanEnd = n0 + SPAN; if (spanEnd > N_NODES) spanEnd = N_NODES;
    const int beg = rowstart[n0];
    const int end = rowstart[spanEnd];
    const int nb = end - beg;
    __syncthreads();

    // ---- phase 1: edge-parallel wt + class sums, batch-4 MLP ----
    for (int i0 = tid; i0 < nb; i0 += 2048) {
        int pv[4]; bool act[4]; float2 sv[4]; int dl[4];
        #pragma unroll
        for (int k = 0; k < 4; ++k) {
            int i = i0 + (k << 9);
            act[k] = i < nb;
            pv[k] = act[k] ? packed[beg + i] : 0;
        }
        #pragma unroll
        for (int k = 0; k < 4; ++k) {
            dl[k] = ((pv[k] >> 20) & 511) - (n0 & 511);
            if (LAST) act[k] = act[k] && ((dl[k] & 2) == 0);  // user/item only
            int s = pv[k] & 0x1FFFF;
            sv[k] = act[k] ? *(const float2*)(ssrc + s * 2) : make_float2(0.f, 0.f);
        }
        #pragma unroll
        for (int k = 0; k < 4; ++k) {
            if (!act[k]) continue;
            int i = i0 + (k << 9);
            int a = (pv[k] >> 17) & 7;
            float2 dv = sdl[dl[k]];
            float2 ev = esc2[a];
            float l0 = dv.x + sv[k].x + ev.x; l0 = l0 >= 0.f ? l0 : 0.2f * l0;
            float l1 = dv.y + sv[k].y + ev.y; l1 = l1 >= 0.f ? l1 : 0.2f * l1;
            float w0 = __expf(l0), w1 = __expf(l1);
            if (i < CAP) { pe[i] = pv[k]; w0b[i] = w0; w1b[i] = w1; }
            atomicAdd(&cls[dl[k] * 10 + a * 2 + 0], w0);
            atomicAdd(&cls[dl[k] * 10 + a * 2 + 1], w1);
        }
    }
    __syncthreads();

    // ---- phase 2: slot-per-node register aggregation, 4-deep MLP ----
    const int lane = tid & 63;
    const int q = lane & 7;                 // channel group: ch q*8..q*8+7
    const int hh = q >> 2;                  // head of this lane's channels
    const int slot = (tid >> 6) * 8 + (lane >> 3);   // 0..63
    const unsigned short* hb = hcurb + q * 8;

    auto fetch = [&](int i, int dlc) -> PE {
        int j = i - beg;
        if (j < CAP) {
            PE r; r.p = pe[j]; r.wt = hh ? w1b[j] : w0b[j]; return r;
        }
        int p = packed[i];                  // overflow fallback (~never)
        int a = (p >> 17) & 7;
        int s = p & 0x1FFFF;
        float2 dv2 = sdl[dlc];
        float2 ev2 = esc2[a];
        float lg = (hh ? dv2.y : dv2.x) + ssrc[s * 2 + hh] + (hh ? ev2.y : ev2.x);
        lg = lg >= 0.f ? lg : 0.2f * lg;
        PE r; r.p = p; r.wt = __expf(lg); return r;
    };

    auto process_node = [&](int myn, float o[8]) {
        const int dl = myn - n0;
        const int b0 = rowstart[myn];
        const int b1 = rowstart[myn + 1];
        float4 a0 = make_float4(0.f, 0.f, 0.f, 0.f);
        float4 a1 = make_float4(0.f, 0.f, 0.f, 0.f);
#define ACC8(wt, hv) do { \
        a0.x += (wt) * bf_lo((hv).x); a0.y += (wt) * bf_hi((hv).x); \
        a0.z += (wt) * bf_lo((hv).y); a0.w += (wt) * bf_hi((hv).y); \
        a1.x += (wt) * bf_lo((hv).z); a1.y += (wt) * bf_hi((hv).z); \
        a1.z += (wt) * bf_lo((hv).w); a1.w += (wt) * bf_hi((hv).w); \
    } while (0)
        int i = b0;
        for (; i + 4 <= b1; i += 4) {
            PE e0 = fetch(i, dl);
            PE e1 = fetch(i + 1, dl);
            PE e2 = fetch(i + 2, dl);
            PE e3 = fetch(i + 3, dl);
            uint4 h0 = *(const uint4*)(hb + (size_t)(e0.p & 0x1FFFF) * HC);
            uint4 h1 = *(const uint4*)(hb + (size_t)(e1.p & 0x1FFFF) * HC);
            uint4 h2 = *(const uint4*)(hb + (size_t)(e2.p & 0x1FFFF) * HC);
            uint4 h3 = *(const uint4*)(hb + (size_t)(e3.p & 0x1FFFF) * HC);
            ACC8(e0.wt, h0);
            ACC8(e1.wt, h1);
            ACC8(e2.wt, h2);
            ACC8(e3.wt, h3);
        }
        for (; i < b1; ++i) {
            PE e0 = fetch(i, dl);
            uint4 h0 = *(const uint4*)(hb + (size_t)(e0.p & 0x1FFFF) * HC);
            ACC8(e0.wt, h0);
        }
#undef ACC8
        // epilogue: fold class sums, normalize, bias, elu
        float ssum = 0.f;
        const float* ef = eemb_l + q * 8;
        #pragma unroll
        for (int a = 0; a < ECLS; ++a) {
            float c = cls[dl * 10 + a * 2 + hh];
            ssum += c;
            float4 e0 = *(const float4*)(ef + a * HC);
            float4 e1 = *(const float4*)(ef + a * HC + 4);
            a0.x += c * e0.x; a0.y += c * e0.y; a0.z += c * e0.z; a0.w += c * e0.w;
            a1.x += c * e1.x; a1.y += c * e1.y; a1.z += c * e1.z; a1.w += c * e1.w;
        }
        float inv = 1.f / (ssum + 1e-16f);
        float4 bv0 = *(const float4*)(bias_l + q * 8);
        float4 bv1 = *(const float4*)(bias_l + q * 8 + 4);
        o[0] = a0.x * inv + bv0.x;
        o[1] = a0.y * inv + bv0.y;
        o[2] = a0.z * inv + bv0.z;
        o[3] = a0.w * inv + bv0.w;
        o[4] = a1.x * inv + bv1.x;
        o[5] = a1.y * inv + bv1.y;
        o[6] = a1.z * inv + bv1.z;
        o[7] = a1.w * inv + bv1.w;
        #pragma unroll
        for (int k = 0; k < 8; ++k)
            o[k] = o[k] > 0.f ? o[k] : (__expf(o[k]) - 1.f);
    };

    if (!LAST) {
        for (int nn = slot; nn < SPAN; nn += 64) {
            int myn = n0 + nn;
            if (myn >= N_NODES) break;
            float o[8];
            process_node(myn, o);
            unsigned int u0 = (unsigned int)f2bf(o[0]) | ((unsigned int)f2bf(o[1]) << 16);
            unsigned int u1 = (unsigned int)f2bf(o[2]) | ((unsigned int)f2bf(o[3]) << 16);
            unsigned int u2 = (unsigned int)f2bf(o[4]) | ((unsigned int)f2bf(o[5]) << 16);
            unsigned int u3 = (unsigned int)f2bf(o[6]) | ((unsigned int)f2bf(o[7]) << 16);
            *(uint4*)(actnext + (size_t)myn * HC + q * 8) = make_uint4(u0, u1, u2, u3);
        }
    } else {
        int gp = blockIdx.x * 32 + (slot >> 1);
        if (gp < NPAIRS) {
            int myn = n0 + (slot >> 1) * 4 + (slot & 1);   // user 4j / item 4j+1
            float o[8];
            process_node(myn, o);
            // partner node's same channels live at lane^8 (slot^1)
            float pd = 0.f;
            #pragma unroll
            for (int k = 0; k < 8; ++k) pd += o[k] * __shfl_xor(o[k], 8, 64);
            pd += __shfl_xor(pd, 1, 64);
            pd += __shfl_xor(pd, 2, 64);
            pd += __shfl_xor(pd, 4, 64);
            if (((slot & 1) == 0) && (q == 0)) out[gp] = pd;
        }
    }
}

// ---------------- launch ----------------
extern "C" void kernel_launch(void* const* d_in, const int* in_sizes, int n_in,
                              void* d_out, int out_size, void* d_ws, size_t ws_size,
                              hipStream_t stream) {
    const float* x       = (const float*)d_in[0];   // [N,4]
    const float* W0      = (const float*)d_in[1];   // [4,64]
    const float* W13     = (const float*)d_in[2];   // [3,64,64]
    const float* eemb    = (const float*)d_in[3];   // [4,5,64]
    const float* att_src = (const float*)d_in[4];   // [4,2,32]
    const float* att_dst = (const float*)d_in[5];   // [4,2,32]
    const float* bias    = (const float*)d_in[6];   // [4,64]
    const int*   eidx    = (const int*)d_in[7];     // [2,E]
    const int*   eattr   = (const int*)d_in[8];     // [E]
    float* out = (float*)d_out;

    const int* src = eidx;
    const int* dst = eidx + N_EDGES;

    char* wsb = (char*)d_ws;
    size_t off = 0;
    auto alloc = [&](size_t bytes) { char* p = wsb + off; off += (bytes + 255) & ~(size_t)255; return p; };
    unsigned short* hcurb  = (unsigned short*)alloc((size_t)N_NODES * HC * 2);
    unsigned short* actB   = (unsigned short*)alloc((size_t)N_NODES * HC * 2);
    float*          ssrc   = (float*)alloc((size_t)N_NODES * 2 * 4);
    float*          sdst   = (float*)alloc((size_t)N_NODES * 2 * 4);
    float*          escore = (float*)alloc(NLAYERS * ECLS * NHEADS * 4);
    int*            bh     = (int*)alloc((size_t)NBUCK * NBLK * 4);
    int*            bbase  = (int*)alloc((size_t)NBUCK * NBLK * 4);
    int*            part   = (int*)alloc(256 * 4);
    int*            rowstart = (int*)alloc(((size_t)N_NODES + 1) * 4);
    int*            bkt    = (int*)alloc((size_t)N_EDGES * 4);
    int*            packed = (int*)alloc((size_t)N_EDGES * 4);

    // ---- CSR build P1 + layer-0 linear + escore (merged) ----
    k_chist_lin0<<<NBLK + LIN0_BLOCKS + 1, 256, 0, stream>>>(
        dst, bh, x, W0, att_src, att_dst, hcurb, ssrc, sdst, eemb, escore);
    k_s1<<<NBUCK, NBLK, 0, stream>>>(bh, bbase, part);
    k_cscatter<<<NBLK, 256, 0, stream>>>(src, dst, eattr, bbase, part, bkt);
    k_fine<<<NBUCK, 512, 0, stream>>>(part, bkt, packed, rowstart);

    const int EDGE_GRID = (N_NODES + 127) / 128;   // 782

    for (int l = 0; l < NLAYERS; ++l) {
        if (l > 0) {
            k_linmfma<<<512, 256, 0, stream>>>(
                actB, W13 + (size_t)(l - 1) * HC * HC,
                att_src + l * HC, att_dst + l * HC, hcurb, ssrc, sdst);
        }
        const float* esl = escore + l * ECLS * NHEADS;
        const float* el  = eemb + (size_t)l * ECLS * HC;
        const float* bl  = bias + l * HC;
        if (l < NLAYERS - 1)
            k_edge4<false><<<EDGE_GRID, 512, 0, stream>>>(
                rowstart, packed, ssrc, sdst, esl, hcurb, el, bl, actB, nullptr);
        else
            k_edge4<true><<<EDGE_GRID, 512, 0, stream>>>(
                rowstart, packed, ssrc, sdst, esl, hcurb, el, bl, nullptr, out);
    }
}

// Round 6
// 330.631 us; speedup vs baseline: 1.3856x; 1.1117x over previous
//
#include <hip/hip_runtime.h>
#include <hip/hip_bf16.h>
#include <math.h>

#define N_NODES 100000
#define N_EDGES 1600000
#define NPAIRS 25000
#define HC 64          // H*C
#define NHEADS 2
#define NLAYERS 4
#define ECLS 5
#define NBUCK 196              // ceil(N / 512); bucket = dst >> 9
#define NBLK 512               // coarse pass blocks
#define EPB (N_EDGES / NBLK)   // 3125 edges per coarse block (exact)
#define NGRP (N_NODES / 16)    // 6250 16-node groups (exact)
#define LIN0_BLOCKS 1024
#define FCAP 12288             // k_fine LDS staging capacity (avg bucket ~8163)

typedef __attribute__((ext_vector_type(8))) short short8;
typedef __attribute__((ext_vector_type(4))) float floatx4;
typedef __attribute__((ext_vector_type(4))) unsigned int uintx4;
union F8 { uint4 u; short8 s; };

struct PE { int p; float wt; };

// bf16 (stored as ushort) -> f32
__device__ inline float bf_lo(unsigned int u) { return __uint_as_float(u << 16); }
__device__ inline float bf_hi(unsigned int u) { return __uint_as_float(u & 0xffff0000u); }
// f32 -> bf16 bits, round-to-nearest-even
__device__ inline unsigned short f2bf(float f) {
    unsigned int u = __float_as_uint(f);
    u += 0x7FFFu + ((u >> 16) & 1u);
    return (unsigned short)(u >> 16);
}

// ---------------- CSR P1 + layer-0 linear + escore (merged) ----------------
// Blocks [0,NBLK): per-(bucket,block) histogram. [NBLK, NBLK+LIN0): lin0.
// Block NBLK+LIN0: escore table (40 dots).
__global__ void k_chist_lin0(const int* __restrict__ dst, int* __restrict__ bh,
                             const float* __restrict__ in,
                             const float* __restrict__ W,        // [4][64]
                             const float* __restrict__ asrc, const float* __restrict__ adst,
                             unsigned short* __restrict__ hcurb,
                             float* __restrict__ ssrc, float* __restrict__ sdst,
                             const float* __restrict__ eemb, float* __restrict__ escore) {
    int tid = threadIdx.x;
    if (blockIdx.x < NBLK) {
        __shared__ int lh[NBUCK];
        int blk = blockIdx.x;
        for (int i = tid; i < NBUCK; i += 256) lh[i] = 0;
        __syncthreads();
        int s = blk * EPB;
        for (int i = tid; i < EPB; i += 256) atomicAdd(&lh[dst[s + i] >> 9], 1);
        __syncthreads();
        for (int i = tid; i < NBUCK; i += 256) bh[i * NBLK + blk] = lh[i];
        return;
    }
    if (blockIdx.x >= NBLK + LIN0_BLOCKS) {
        if (tid < NLAYERS * ECLS * NHEADS) {
            int l = tid / (ECLS * NHEADS);
            int r = tid % (ECLS * NHEADS);
            int c = r >> 1;
            int h = r & 1;
            float s = 0.f;
            const float* ev = eemb + l * ECLS * HC + c * HC + h * 32;
            const float* av = asrc + l * HC + h * 32;   // att_src base passed
            for (int k = 0; k < 32; ++k) s += ev[k] * av[k];
            escore[tid] = s;
        }
        return;
    }
    int j = tid & 63;
    int wid = ((blockIdx.x - NBLK) * 256 + tid) >> 6;
    int nwaves = LIN0_BLOCKS * 4;

    float w0 = W[0 * HC + j], w1 = W[1 * HC + j], w2 = W[2 * HC + j], w3 = W[3 * HC + j];
    int head = j >> 5;
    int c = j & 31;
    float as = asrc[head * 32 + c];
    float ad = adst[head * 32 + c];

    for (int n = wid; n < N_NODES; n += nwaves) {
        int nu = __builtin_amdgcn_readfirstlane(n);
        float4 r = *(const float4*)(in + (size_t)nu * 4);
        float acc = r.x * w0 + r.y * w1 + r.z * w2 + r.w * w3;
        hcurb[(size_t)nu * HC + j] = f2bf(acc);
        float ps = acc * as;
        float pd = acc * ad;
        for (int off = 16; off > 0; off >>= 1) {
            ps += __shfl_down(ps, off, 32);
            pd += __shfl_down(pd, off, 32);
        }
        if (c == 0) {
            ssrc[nu * 2 + head] = ps;
            sdst[nu * 2 + head] = pd;
        }
    }
}

// P2a: per-bucket exclusive scan of the NBLK per-block counts; raw bucket
// sums to part[] (consumers scan part locally — no k_s2 dispatch).
__global__ void k_s1(const int* __restrict__ bh, int* __restrict__ bbase,
                     int* __restrict__ part) {
    __shared__ int tmp[NBLK];
    int tid = threadIdx.x;
    int i = blockIdx.x * NBLK + tid;
    int v = bh[i];
    tmp[tid] = v;
    __syncthreads();
    for (int off = 1; off < NBLK; off <<= 1) {
        int t = (tid >= off) ? tmp[tid - off] : 0;
        __syncthreads();
        tmp[tid] += t;
        __syncthreads();
    }
    bbase[i] = tmp[tid] - v;
    if (tid == NBLK - 1) part[blockIdx.x] = tmp[NBLK - 1];
}

// P3: coarse scatter, LDS-STAGED -> coalesced global writes.
// part[] holds raw bucket sums; scan locally.
__global__ void k_cscatter(const int* __restrict__ src, const int* __restrict__ dst,
                           const int* __restrict__ attr, const int* __restrict__ bbase,
                           const int* __restrict__ part, int* __restrict__ bkt) {
    __shared__ int tmp[256];
    __shared__ int cur[NBUCK];
    __shared__ int gadj[NBUCK];
    __shared__ int stage[EPB];            // 12.5 KB
    __shared__ unsigned char stb[EPB];    // 3.1 KB
    int tid = threadIdx.x, blk = blockIdx.x;
    int pv = (tid < NBUCK) ? part[tid] : 0;
    tmp[tid] = pv;
    __syncthreads();
    for (int off = 1; off < 256; off <<= 1) {
        int t = (tid >= off) ? tmp[tid - off] : 0;
        __syncthreads();
        tmp[tid] += t;
        __syncthreads();
    }
    if (tid < NBUCK) gadj[tid] = tmp[tid] - pv;
    if (tid < NBUCK) cur[tid] = 0;
    __syncthreads();
    int s0 = blk * EPB;
    for (int i = tid; i < EPB; i += 256) atomicAdd(&cur[dst[s0 + i] >> 9], 1);
    __syncthreads();
    int v = (tid < NBUCK) ? cur[tid] : 0;
    tmp[tid] = v;
    __syncthreads();
    for (int off = 1; off < 256; off <<= 1) {
        int t = (tid >= off) ? tmp[tid - off] : 0;
        __syncthreads();
        tmp[tid] += t;
        __syncthreads();
    }
    int ex = tmp[tid] - v;
    if (tid < NBUCK) {
        cur[tid] = ex;                                         // local cursor
        gadj[tid] += bbase[tid * NBLK + blk] - ex;             // global - local
    }
    __syncthreads();
    for (int i = tid; i < EPB; i += 256) {
        int e = s0 + i;
        int d = dst[e];
        int b = d >> 9;
        int pos = atomicAdd(&cur[b], 1);
        stage[pos] = src[e] | (attr[e] << 17) | ((d & 511) << 20);
        stb[pos] = (unsigned char)b;
    }
    __syncthreads();
    for (int i = tid; i < EPB; i += 256)
        bkt[gadj[stb[i]] + i] = stage[i];
}

// P4: fine sort within each bucket, LDS-STAGED (fallback if > FCAP).
__global__ void k_fine(const int* __restrict__ part, const int* __restrict__ bkt,
                       int* __restrict__ packed, int* __restrict__ rowstart) {
    __shared__ int hist[512];
    __shared__ int cur[512];
    __shared__ int pscan[512];
    __shared__ int stage[FCAP];           // 48 KB
    int b = blockIdx.x, tid = threadIdx.x;   // 512 threads
    int pv = (tid < NBUCK) ? part[tid] : 0;
    pscan[tid] = pv;
    __syncthreads();
    for (int off = 1; off < 512; off <<= 1) {
        int t = (tid >= off) ? pscan[tid - off] : 0;
        __syncthreads();
        pscan[tid] += t;
        __syncthreads();
    }
    int base = (b == 0) ? 0 : pscan[b - 1];
    int bend = pscan[b];
    int nb = bend - base;
    hist[tid] = 0;
    __syncthreads();
    for (int i = tid; i < nb; i += 512)
        atomicAdd(&hist[(bkt[base + i] >> 20) & 0x1FF], 1);
    __syncthreads();
    int v = hist[tid];
    for (int off = 1; off < 512; off <<= 1) {
        int t = (tid >= off) ? hist[tid - off] : 0;
        __syncthreads();
        hist[tid] += t;
        __syncthreads();
    }
    int excl = hist[tid] - v;
    int node = (b << 9) + tid;
    if (node <= N_NODES) rowstart[node] = base + excl;
    cur[tid] = excl;
    __syncthreads();
    if (nb <= FCAP) {
        for (int i = tid; i < nb; i += 512) {
            int p = bkt[base + i];
            int r = atomicAdd(&cur[(p >> 20) & 0x1FF], 1);
            stage[r] = p;
        }
        __syncthreads();
        for (int i = tid; i < nb; i += 512) packed[base + i] = stage[i];
    } else {
        for (int i = tid; i < nb; i += 512) {
            int p = bkt[base + i];
            int r = atomicAdd(&cur[(p >> 20) & 0x1FF], 1);
            packed[base + r] = p;
        }
    }
}

// ---------------- MFMA linear (layers 1..3) ----------------
__global__ void k_linmfma(const unsigned short* __restrict__ actB,
                          const float* __restrict__ Wl,       // [64][64] fp32
                          const float* __restrict__ asrc,     // [64]
                          const float* __restrict__ adst,     // [64]
                          unsigned short* __restrict__ hcurb,
                          float* __restrict__ ssrc, float* __restrict__ sdst) {
    __shared__ uint4 WB[512];
    __shared__ unsigned short Cb[4][1024];
    int tid = threadIdx.x;
    int lane = tid & 63;
    int w = tid >> 6;
    int q = lane >> 4;
    int c = lane & 15;

    for (int rid = tid; rid < 512; rid += 256) {
        int kk = rid >> 8;
        int t  = (rid >> 6) & 3;
        int ln = rid & 63;
        int qq = ln >> 4, cc = ln & 15;
        unsigned int u[4];
        #pragma unroll
        for (int jj = 0; jj < 4; ++jj) {
            float v0 = Wl[(kk * 32 + qq * 8 + jj * 2 + 0) * 64 + 16 * t + cc];
            float v1 = Wl[(kk * 32 + qq * 8 + jj * 2 + 1) * 64 + 16 * t + cc];
            u[jj] = (unsigned int)f2bf(v0) | ((unsigned int)f2bf(v1) << 16);
        }
        WB[rid] = make_uint4(u[0], u[1], u[2], u[3]);
    }
    __syncthreads();

    short8 bfr[2][4];
    #pragma unroll
    for (int kk = 0; kk < 2; ++kk)
        #pragma unroll
        for (int t = 0; t < 4; ++t) {
            F8 tmp; tmp.u = WB[(kk * 4 + t) * 64 + lane];
            bfr[kk][t] = tmp.s;
        }

    float as_[4], ad_[4];
    #pragma unroll
    for (int t = 0; t < 4; ++t) {
        as_[t] = asrc[16 * t + c];
        ad_[t] = adst[16 * t + c];
    }

    int wid = (blockIdx.x * 256 + tid) >> 6;
    int nwaves = gridDim.x * 4;

    for (int g = wid; g < NGRP; g += nwaves) {
        int base = g * 16;
        F8 a0, a1;
        a0.u = *(const uint4*)(actB + (size_t)(base + c) * HC + q * 8);
        a1.u = *(const uint4*)(actB + (size_t)(base + c) * HC + 32 + q * 8);

        floatx4 acc[4];
        #pragma unroll
        for (int t = 0; t < 4; ++t) {
            acc[t] = (floatx4){0.f, 0.f, 0.f, 0.f};
            acc[t] = __builtin_amdgcn_mfma_f32_16x16x32_bf16(a0.s, bfr[0][t], acc[t], 0, 0, 0);
            acc[t] = __builtin_amdgcn_mfma_f32_16x16x32_bf16(a1.s, bfr[1][t], acc[t], 0, 0, 0);
        }

        #pragma unroll
        for (int r = 0; r < 4; ++r) {
            float h0s = acc[0][r] * as_[0] + acc[1][r] * as_[1];
            float h1s = acc[2][r] * as_[2] + acc[3][r] * as_[3];
            float h0d = acc[0][r] * ad_[0] + acc[1][r] * ad_[1];
            float h1d = acc[2][r] * ad_[2] + acc[3][r] * ad_[3];
            #pragma unroll
            for (int off = 1; off < 16; off <<= 1) {
                h0s += __shfl_xor(h0s, off, 64);
                h1s += __shfl_xor(h1s, off, 64);
                h0d += __shfl_xor(h0d, off, 64);
                h1d += __shfl_xor(h1d, off, 64);
            }
            if (c == 0) {
                int node = base + q * 4 + r;
                *(float2*)(ssrc + node * 2) = make_float2(h0s, h1s);
                *(float2*)(sdst + node * 2) = make_float2(h0d, h1d);
            }
        }

        #pragma unroll
        for (int t = 0; t < 4; ++t)
            #pragma unroll
            for (int r = 0; r < 4; ++r)
                Cb[w][(q * 4 + r) * 64 + 16 * t + c] = f2bf(acc[t][r]);
        __builtin_amdgcn_wave_barrier();
        const uint4* cf = (const uint4*)&Cb[w][0];
        uint4* gout = (uint4*)(hcurb + (size_t)base * HC);
        gout[lane] = cf[lane];
        gout[64 + lane] = cf[64 + lane];
        __builtin_amdgcn_wave_barrier();
    }
}

// ---------------- fused edge pipeline (v6: v3 + batch-2 phase 1) ----------
// 256 threads, 32 nodes per block (64-node span, pairs only, for LAST).
// Phase 1 (edge-parallel, BATCH-2): issue both packed loads, then both
//   ssrc gathers, then compute — halves the per-thread serialized
//   latency chain (in-order waves stall at first use).
// Phase 2 (slot-per-node, 8 lanes/node, 8 ch/lane): register accumulation,
//   4 gathers in flight, scalar tail. Identical to v3.
template <bool LAST>
__global__ __launch_bounds__(256)
void k_edge2(const int* __restrict__ rowstart, const int* __restrict__ packed,
             const float* __restrict__ ssrc, const float* __restrict__ sdst,
             const float* __restrict__ escore_l,   // [5][2]
             const unsigned short* __restrict__ hcurb, // [N][64] bf16
             const float* __restrict__ eemb_l,     // [5][64]
             const float* __restrict__ bias_l,     // [64]
             unsigned short* __restrict__ actnext, float* __restrict__ out) {
    constexpr int SPAN = LAST ? 64 : 32;   // node span per block
    constexpr int CAP  = LAST ? 1440 : 800; // staging cap (mean 1024/512, >11 sigma)
    __shared__ float4 ebuf[CAP];           // {p bits, w0, w1, pad}
    __shared__ float  cls[SPAN * 10];      // [node][class][head] weight sums
    __shared__ float2 sdl[SPAN];           // sdst for span
    __shared__ float2 esc2[ECLS];

    const int tid = threadIdx.x;
    const int n0 = blockIdx.x * SPAN;

    for (int i = tid; i < SPAN * 10; i += 256) cls[i] = 0.f;
    if (tid < ECLS) esc2[tid] = ((const float2*)escore_l)[tid];
    if (tid < SPAN) {
        int nn = n0 + tid; if (nn > N_NODES - 1) nn = N_NODES - 1;
        sdl[tid] = ((const float2*)sdst)[nn];
    }
    int spanEnd = n0 + SPAN; if (spanEnd > N_NODES) spanEnd = N_NODES;
    const int beg = rowstart[n0];
    const int end = rowstart[spanEnd];
    __syncthreads();

    // ---- phase 1: edge-parallel wt + class sums, batch-2 MLP ----
    const int nb = end - beg;
    for (int i0 = tid; i0 < nb; i0 += 512) {
        const int i1 = i0 + 256;
        const bool has1 = i1 < nb;
        int p0 = __builtin_nontemporal_load(&packed[beg + i0]);
        int p1 = has1 ? __builtin_nontemporal_load(&packed[beg + i1]) : 0;
        int dl0 = ((p0 >> 20) & 511) - (n0 & 511);
        int dl1 = ((p1 >> 20) & 511) - (n0 & 511);
        bool a0 = (!LAST || ((dl0 & 2) == 0));
        bool a1 = has1 && (!LAST || ((dl1 & 2) == 0));
        int s0 = p0 & 0x1FFFF;
        int s1 = p1 & 0x1FFFF;
        float2 sv0 = make_float2(0.f, 0.f), sv1 = make_float2(0.f, 0.f);
        if (a0) sv0 = *(const float2*)(ssrc + s0 * 2);
        if (a1) sv1 = *(const float2*)(ssrc + s1 * 2);
        if (a0) {
            int a = (p0 >> 17) & 7;
            float2 dv = sdl[dl0];
            float2 ev = esc2[a];
            float l0 = dv.x + sv0.x + ev.x; l0 = l0 >= 0.f ? l0 : 0.2f * l0;
            float l1 = dv.y + sv0.y + ev.y; l1 = l1 >= 0.f ? l1 : 0.2f * l1;
            float w0 = __expf(l0), w1 = __expf(l1);
            if (i0 < CAP) ebuf[i0] = make_float4(__int_as_float(p0), w0, w1, 0.f);
            atomicAdd(&cls[dl0 * 10 + a * 2 + 0], w0);
            atomicAdd(&cls[dl0 * 10 + a * 2 + 1], w1);
        }
        if (a1) {
            int a = (p1 >> 17) & 7;
            float2 dv = sdl[dl1];
            float2 ev = esc2[a];
            float l0 = dv.x + sv1.x + ev.x; l0 = l0 >= 0.f ? l0 : 0.2f * l0;
            float l1 = dv.y + sv1.y + ev.y; l1 = l1 >= 0.f ? l1 : 0.2f * l1;
            float w0 = __expf(l0), w1 = __expf(l1);
            if (i1 < CAP) ebuf[i1] = make_float4(__int_as_float(p1), w0, w1, 0.f);
            atomicAdd(&cls[dl1 * 10 + a * 2 + 0], w0);
            atomicAdd(&cls[dl1 * 10 + a * 2 + 1], w1);
        }
    }
    __syncthreads();

    // ---- phase 2: slot-per-node register aggregation, 4-deep MLP ----
    const int lane = tid & 63;
    const int q = lane & 7;                 // channel group: ch q*8..q*8+7
    const int hh = q >> 2;                  // head of this lane's channels
    const int slot = (tid >> 6) * 8 + (lane >> 3);   // 0..31
    int myn, pair = 0;
    bool valid = true;
    if (LAST) {
        pair = blockIdx.x * 16 + (slot >> 1);
        valid = pair < NPAIRS;
        myn = n0 + (slot >> 1) * 4 + (slot & 1);     // user 4j / item 4j+1
    } else {
        myn = n0 + slot;
    }
    const int b0 = valid ? rowstart[myn] : 0;
    const int b1 = valid ? rowstart[myn + 1] : 0;
    const unsigned short* hb = hcurb + q * 8;

    float4 a0 = make_float4(0.f, 0.f, 0.f, 0.f);
    float4 a1 = make_float4(0.f, 0.f, 0.f, 0.f);

    auto fetch = [&](int i) -> PE {
        PE r;
        int j = i - beg;
        if (j < CAP) {
            float4 t = ebuf[j];
            r.p = __float_as_int(t.x);
            r.wt = hh ? t.z : t.y;
        } else {                              // overflow fallback (~never)
            int p = packed[i];
            int aa = (p >> 17) & 7;
            int ss = p & 0x1FFFF;
            int dll = ((p >> 20) & 511) - (n0 & 511);
            float2 dv2 = sdl[dll];
            float2 ev2 = esc2[aa];
            float lg = (hh ? dv2.y : dv2.x) + ssrc[ss * 2 + hh] + (hh ? ev2.y : ev2.x);
            lg = lg >= 0.f ? lg : 0.2f * lg;
            r.p = p;
            r.wt = __expf(lg);
        }
        return r;
    };

#define ACC8(wt, hv) do { \
        a0.x += (wt) * bf_lo((hv).x); a0.y += (wt) * bf_hi((hv).x); \
        a0.z += (wt) * bf_lo((hv).y); a0.w += (wt) * bf_hi((hv).y); \
        a1.x += (wt) * bf_lo((hv).z); a1.y += (wt) * bf_hi((hv).z); \
        a1.z += (wt) * bf_lo((hv).w); a1.w += (wt) * bf_hi((hv).w); \
    } while (0)

    int i = b0;
    for (; i + 4 <= b1; i += 4) {             // 4 gathers in flight
        PE e0 = fetch(i);
        PE e1 = fetch(i + 1);
        PE e2 = fetch(i + 2);
        PE e3 = fetch(i + 3);
        uint4 h0 = *(const uint4*)(hb + ((e0.p & 0x1FFFF) << 6));
        uint4 h1 = *(const uint4*)(hb + ((e1.p & 0x1FFFF) << 6));
        uint4 h2 = *(const uint4*)(hb + ((e2.p & 0x1FFFF) << 6));
        uint4 h3 = *(const uint4*)(hb + ((e3.p & 0x1FFFF) << 6));
        ACC8(e0.wt, h0);
        ACC8(e1.wt, h1);
        ACC8(e2.wt, h2);
        ACC8(e3.wt, h3);
    }
    for (; i < b1; ++i) {                     // scalar tail (<=3 edges)
        PE e0 = fetch(i);
        uint4 h0 = *(const uint4*)(hb + ((e0.p & 0x1FFFF) << 6));
        ACC8(e0.wt, h0);
    }
#undef ACC8

    // ---- epilogue: fold class sums, normalize, bias, elu ----
    const int dl = myn - n0;
    float ssum = 0.f;
    const float* ef = eemb_l + q * 8;
    #pragma unroll
    for (int a = 0; a < ECLS; ++a) {
        float c = cls[dl * 10 + a * 2 + hh];
        ssum += c;
        float4 e0 = *(const float4*)(ef + a * HC);
        float4 e1 = *(const float4*)(ef + a * HC + 4);
        a0.x += c * e0.x; a0.y += c * e0.y; a0.z += c * e0.z; a0.w += c * e0.w;
        a1.x += c * e1.x; a1.y += c * e1.y; a1.z += c * e1.z; a1.w += c * e1.w;
    }
    float inv = 1.f / (ssum + 1e-16f);
    float4 bv0 = *(const float4*)(bias_l + q * 8);
    float4 bv1 = *(const float4*)(bias_l + q * 8 + 4);
    float o0 = a0.x * inv + bv0.x; o0 = o0 > 0.f ? o0 : (__expf(o0) - 1.f);
    float o1 = a0.y * inv + bv0.y; o1 = o1 > 0.f ? o1 : (__expf(o1) - 1.f);
    float o2 = a0.z * inv + bv0.z; o2 = o2 > 0.f ? o2 : (__expf(o2) - 1.f);
    float o3 = a0.w * inv + bv0.w; o3 = o3 > 0.f ? o3 : (__expf(o3) - 1.f);
    float o4 = a1.x * inv + bv1.x; o4 = o4 > 0.f ? o4 : (__expf(o4) - 1.f);
    float o5 = a1.y * inv + bv1.y; o5 = o5 > 0.f ? o5 : (__expf(o5) - 1.f);
    float o6 = a1.z * inv + bv1.z; o6 = o6 > 0.f ? o6 : (__expf(o6) - 1.f);
    float o7 = a1.w * inv + bv1.w; o7 = o7 > 0.f ? o7 : (__expf(o7) - 1.f);

    if (!LAST) {
        unsigned int u0 = (unsigned int)f2bf(o0) | ((unsigned int)f2bf(o1) << 16);
        unsigned int u1 = (unsigned int)f2bf(o2) | ((unsigned int)f2bf(o3) << 16);
        unsigned int u2 = (unsigned int)f2bf(o4) | ((unsigned int)f2bf(o5) << 16);
        unsigned int u3 = (unsigned int)f2bf(o6) | ((unsigned int)f2bf(o7) << 16);
        uintx4 uv = (uintx4){u0, u1, u2, u3};
        __builtin_nontemporal_store(uv, (uintx4*)(actnext + (size_t)myn * HC + q * 8));
    } else {
        // pair dot: partner slot is lane^8 (user<->item), then reduce over q
        float pdot = o0 * __shfl_xor(o0, 8, 64)
                   + o1 * __shfl_xor(o1, 8, 64)
                   + o2 * __shfl_xor(o2, 8, 64)
                   + o3 * __shfl_xor(o3, 8, 64)
                   + o4 * __shfl_xor(o4, 8, 64)
                   + o5 * __shfl_xor(o5, 8, 64)
                   + o6 * __shfl_xor(o6, 8, 64)
                   + o7 * __shfl_xor(o7, 8, 64);
        pdot += __shfl_xor(pdot, 1, 64);
        pdot += __shfl_xor(pdot, 2, 64);
        pdot += __shfl_xor(pdot, 4, 64);
        if (valid && ((slot & 1) == 0) && (q == 0)) out[pair] = pdot;
    }
}

// ---------------- launch ----------------
extern "C" void kernel_launch(void* const* d_in, const int* in_sizes, int n_in,
                              void* d_out, int out_size, void* d_ws, size_t ws_size,
                              hipStream_t stream) {
    const float* x       = (const float*)d_in[0];   // [N,4]
    const float* W0      = (const float*)d_in[1];   // [4,64]
    const float* W13     = (const float*)d_in[2];   // [3,64,64]
    const float* eemb    = (const float*)d_in[3];   // [4,5,64]
    const float* att_src = (const float*)d_in[4];   // [4,2,32]
    const float* att_dst = (const float*)d_in[5];   // [4,2,32]
    const float* bias    = (const float*)d_in[6];   // [4,64]
    const int*   eidx    = (const int*)d_in[7];     // [2,E]
    const int*   eattr   = (const int*)d_in[8];     // [E]
    float* out = (float*)d_out;

    const int* src = eidx;
    const int* dst = eidx + N_EDGES;

    char* wsb = (char*)d_ws;
    size_t off = 0;
    auto alloc = [&](size_t bytes) { char* p = wsb + off; off += (bytes + 255) & ~(size_t)255; return p; };
    unsigned short* hcurb  = (unsigned short*)alloc((size_t)N_NODES * HC * 2);
    unsigned short* actB   = (unsigned short*)alloc((size_t)N_NODES * HC * 2);
    float*          ssrc   = (float*)alloc((size_t)N_NODES * 2 * 4);
    float*          sdst   = (float*)alloc((size_t)N_NODES * 2 * 4);
    float*          escore = (float*)alloc(NLAYERS * ECLS * NHEADS * 4);
    int*            bh     = (int*)alloc((size_t)NBUCK * NBLK * 4);
    int*            bbase  = (int*)alloc((size_t)NBUCK * NBLK * 4);
    int*            part   = (int*)alloc(256 * 4);
    int*            rowstart = (int*)alloc(((size_t)N_NODES + 1) * 4);
    int*            bkt    = (int*)alloc((size_t)N_EDGES * 4);
    int*            packed = (int*)alloc((size_t)N_EDGES * 4);

    // ---- CSR build P1 + layer-0 linear + escore (merged) ----
    k_chist_lin0<<<NBLK + LIN0_BLOCKS + 1, 256, 0, stream>>>(
        dst, bh, x, W0, att_src, att_dst, hcurb, ssrc, sdst, eemb, escore);
    k_s1<<<NBUCK, NBLK, 0, stream>>>(bh, bbase, part);
    k_cscatter<<<NBLK, 256, 0, stream>>>(src, dst, eattr, bbase, part, bkt);
    k_fine<<<NBUCK, 512, 0, stream>>>(part, bkt, packed, rowstart);

    for (int l = 0; l < NLAYERS; ++l) {
        if (l > 0) {
            k_linmfma<<<512, 256, 0, stream>>>(
                actB, W13 + (size_t)(l - 1) * HC * HC,
                att_src + l * HC, att_dst + l * HC, hcurb, ssrc, sdst);
        }
        const float* esl = escore + l * ECLS * NHEADS;
        const float* el  = eemb + (size_t)l * ECLS * HC;
        const float* bl  = bias + l * HC;
        if (l < NLAYERS - 1)
            k_edge2<false><<<N_NODES / 32, 256, 0, stream>>>(
                rowstart, packed, ssrc, sdst, esl, hcurb, el, bl, actB, nullptr);
        else
            k_edge2<true><<<(NPAIRS + 15) / 16, 256, 0, stream>>>(
                rowstart, packed, ssrc, sdst, esl, hcurb, el, bl, nullptr, out);
    }
}

// Round 7
// 319.176 us; speedup vs baseline: 1.4354x; 1.0359x over previous
//
#include <hip/hip_runtime.h>
#include <hip/hip_bf16.h>
#include <math.h>

#define N_NODES 100000
#define N_EDGES 1600000
#define HC 64          // H*C
#define NHEADS 2
#define NLAYERS 4
#define ECLS 5
#define NBUCK 196              // ceil(N / 512); bucket = dst >> 9
#define NBLK 512               // coarse pass blocks
#define EPB (N_EDGES / NBLK)   // 3125 edges per coarse block (exact)
#define NGRP (N_NODES / 16)    // 6250 16-node groups (exact)
#define LIN0_BLOCKS 1024
#define FCAP 12288             // k_fine LDS staging capacity (avg bucket ~8163)
#define CHS 68                 // chbuf slot stride (floats): conflict-free b128

typedef __attribute__((ext_vector_type(8))) short short8;
typedef __attribute__((ext_vector_type(4))) float floatx4;
union F8 { uint4 u; short8 s; };

// bf16 (stored as ushort) -> f32
__device__ inline float bf_lo(unsigned int u) { return __uint_as_float(u << 16); }
__device__ inline float bf_hi(unsigned int u) { return __uint_as_float(u & 0xffff0000u); }
// f32 -> bf16 bits, round-to-nearest-even
__device__ inline unsigned short f2bf(float f) {
    unsigned int u = __float_as_uint(f);
    u += 0x7FFFu + ((u >> 16) & 1u);
    return (unsigned short)(u >> 16);
}

// ---------------- CSR P1 + layer-0 linear + escore (merged) ----------------
// Blocks [0,NBLK): per-(bucket,block) histogram. [NBLK, NBLK+LIN0): lin0.
// Block NBLK+LIN0: escore table (40 dots).
__global__ void k_chist_lin0(const int* __restrict__ dst, int* __restrict__ bh,
                             const float* __restrict__ in,
                             const float* __restrict__ W,        // [4][64]
                             const float* __restrict__ asrc, const float* __restrict__ adst,
                             unsigned short* __restrict__ hcurb,
                             float* __restrict__ ssrc, float* __restrict__ sdst,
                             const float* __restrict__ eemb, float* __restrict__ escore) {
    int tid = threadIdx.x;
    if (blockIdx.x < NBLK) {
        __shared__ int lh[NBUCK];
        int blk = blockIdx.x;
        for (int i = tid; i < NBUCK; i += 256) lh[i] = 0;
        __syncthreads();
        int s = blk * EPB;
        for (int i = tid; i < EPB; i += 256) atomicAdd(&lh[dst[s + i] >> 9], 1);
        __syncthreads();
        for (int i = tid; i < NBUCK; i += 256) bh[i * NBLK + blk] = lh[i];
        return;
    }
    if (blockIdx.x >= NBLK + LIN0_BLOCKS) {
        if (tid < NLAYERS * ECLS * NHEADS) {
            int l = tid / (ECLS * NHEADS);
            int r = tid % (ECLS * NHEADS);
            int c = r >> 1;
            int h = r & 1;
            float s = 0.f;
            const float* ev = eemb + l * ECLS * HC + c * HC + h * 32;
            const float* av = asrc + l * HC + h * 32;   // att_src base passed
            for (int k = 0; k < 32; ++k) s += ev[k] * av[k];
            escore[tid] = s;
        }
        return;
    }
    int j = tid & 63;
    int wid = ((blockIdx.x - NBLK) * 256 + tid) >> 6;
    int nwaves = LIN0_BLOCKS * 4;

    float w0 = W[0 * HC + j], w1 = W[1 * HC + j], w2 = W[2 * HC + j], w3 = W[3 * HC + j];
    int head = j >> 5;
    int c = j & 31;
    float as = asrc[head * 32 + c];
    float ad = adst[head * 32 + c];

    for (int n = wid; n < N_NODES; n += nwaves) {
        int nu = __builtin_amdgcn_readfirstlane(n);
        float4 r = *(const float4*)(in + (size_t)nu * 4);
        float acc = r.x * w0 + r.y * w1 + r.z * w2 + r.w * w3;
        hcurb[(size_t)nu * HC + j] = f2bf(acc);
        float ps = acc * as;
        float pd = acc * ad;
        for (int off = 16; off > 0; off >>= 1) {
            ps += __shfl_down(ps, off, 32);
            pd += __shfl_down(pd, off, 32);
        }
        if (c == 0) {
            ssrc[nu * 2 + head] = ps;
            sdst[nu * 2 + head] = pd;
        }
    }
}

// P2a: per-bucket exclusive scan of the NBLK per-block counts; raw bucket
// sums to part[] (consumers scan part locally — no k_s2 dispatch).
__global__ void k_s1(const int* __restrict__ bh, int* __restrict__ bbase,
                     int* __restrict__ part) {
    __shared__ int tmp[NBLK];
    int tid = threadIdx.x;
    int i = blockIdx.x * NBLK + tid;
    int v = bh[i];
    tmp[tid] = v;
    __syncthreads();
    for (int off = 1; off < NBLK; off <<= 1) {
        int t = (tid >= off) ? tmp[tid - off] : 0;
        __syncthreads();
        tmp[tid] += t;
        __syncthreads();
    }
    bbase[i] = tmp[tid] - v;
    if (tid == NBLK - 1) part[blockIdx.x] = tmp[NBLK - 1];
}

// P3: coarse scatter, LDS-STAGED -> coalesced global writes.
// part[] holds raw bucket sums; scan locally.
__global__ void k_cscatter(const int* __restrict__ src, const int* __restrict__ dst,
                           const int* __restrict__ attr, const int* __restrict__ bbase,
                           const int* __restrict__ part, int* __restrict__ bkt) {
    __shared__ int tmp[256];
    __shared__ int cur[NBUCK];
    __shared__ int gadj[NBUCK];
    __shared__ int stage[EPB];            // 12.5 KB
    __shared__ unsigned char stb[EPB];    // 3.1 KB
    int tid = threadIdx.x, blk = blockIdx.x;
    // local exclusive scan of part -> gadj (bucket global base)
    int pv = (tid < NBUCK) ? part[tid] : 0;
    tmp[tid] = pv;
    __syncthreads();
    for (int off = 1; off < 256; off <<= 1) {
        int t = (tid >= off) ? tmp[tid - off] : 0;
        __syncthreads();
        tmp[tid] += t;
        __syncthreads();
    }
    if (tid < NBUCK) gadj[tid] = tmp[tid] - pv;
    if (tid < NBUCK) cur[tid] = 0;
    for (int i = tid + 256; i < NBUCK; i += 256) cur[i] = 0;  // (NBUCK<256: no-op)
    __syncthreads();
    int s0 = blk * EPB;
    for (int i = tid; i < EPB; i += 256) atomicAdd(&cur[dst[s0 + i] >> 9], 1);
    __syncthreads();
    int v = (tid < NBUCK) ? cur[tid] : 0;
    tmp[tid] = v;
    __syncthreads();
    for (int off = 1; off < 256; off <<= 1) {
        int t = (tid >= off) ? tmp[tid - off] : 0;
        __syncthreads();
        tmp[tid] += t;
        __syncthreads();
    }
    int ex = tmp[tid] - v;
    if (tid < NBUCK) {
        cur[tid] = ex;                                         // local cursor
        gadj[tid] += bbase[tid * NBLK + blk] - ex;             // global - local
    }
    __syncthreads();
    for (int i = tid; i < EPB; i += 256) {
        int e = s0 + i;
        int d = dst[e];
        int b = d >> 9;
        int pos = atomicAdd(&cur[b], 1);
        stage[pos] = src[e] | (attr[e] << 17) | ((d & 511) << 20);
        stb[pos] = (unsigned char)b;
    }
    __syncthreads();
    for (int i = tid; i < EPB; i += 256)
        bkt[gadj[stb[i]] + i] = stage[i];
}

// P4: fine sort within each bucket, LDS-STAGED (fallback if > FCAP).
// part[] raw; local inclusive scan for [base, bend).
__global__ void k_fine(const int* __restrict__ part, const int* __restrict__ bkt,
                       int* __restrict__ packed, int* __restrict__ rowstart) {
    __shared__ int hist[512];
    __shared__ int cur[512];
    __shared__ int pscan[512];
    __shared__ int stage[FCAP];           // 48 KB
    int b = blockIdx.x, tid = threadIdx.x;   // 512 threads
    int pv = (tid < NBUCK) ? part[tid] : 0;
    pscan[tid] = pv;
    __syncthreads();
    for (int off = 1; off < 512; off <<= 1) {
        int t = (tid >= off) ? pscan[tid - off] : 0;
        __syncthreads();
        pscan[tid] += t;
        __syncthreads();
    }
    int base = (b == 0) ? 0 : pscan[b - 1];
    int bend = pscan[b];
    int nb = bend - base;
    hist[tid] = 0;
    __syncthreads();
    for (int i = tid; i < nb; i += 512)
        atomicAdd(&hist[(bkt[base + i] >> 20) & 0x1FF], 1);
    __syncthreads();
    int v = hist[tid];
    for (int off = 1; off < 512; off <<= 1) {
        int t = (tid >= off) ? hist[tid - off] : 0;
        __syncthreads();
        hist[tid] += t;
        __syncthreads();
    }
    int excl = hist[tid] - v;
    int node = (b << 9) + tid;
    if (node <= N_NODES) rowstart[node] = base + excl;
    cur[tid] = excl;
    __syncthreads();
    if (nb <= FCAP) {
        for (int i = tid; i < nb; i += 512) {
            int p = bkt[base + i];
            int r = atomicAdd(&cur[(p >> 20) & 0x1FF], 1);
            stage[r] = p;
        }
        __syncthreads();
        for (int i = tid; i < nb; i += 512) packed[base + i] = stage[i];
    } else {
        for (int i = tid; i < nb; i += 512) {
            int p = bkt[base + i];
            int r = atomicAdd(&cur[(p >> 20) & 0x1FF], 1);
            packed[base + r] = p;
        }
    }
}

// ---------------- MFMA linear (layers 1..3) ----------------
__global__ void k_linmfma(const unsigned short* __restrict__ actB,
                          const float* __restrict__ Wl,       // [64][64] fp32
                          const float* __restrict__ asrc,     // [64]
                          const float* __restrict__ adst,     // [64]
                          unsigned short* __restrict__ hcurb,
                          float* __restrict__ ssrc, float* __restrict__ sdst) {
    __shared__ uint4 WB[512];
    __shared__ unsigned short Cb[4][1024];
    int tid = threadIdx.x;
    int lane = tid & 63;
    int w = tid >> 6;
    int q = lane >> 4;
    int c = lane & 15;

    for (int rid = tid; rid < 512; rid += 256) {
        int kk = rid >> 8;
        int t  = (rid >> 6) & 3;
        int ln = rid & 63;
        int qq = ln >> 4, cc = ln & 15;
        unsigned int u[4];
        #pragma unroll
        for (int jj = 0; jj < 4; ++jj) {
            float v0 = Wl[(kk * 32 + qq * 8 + jj * 2 + 0) * 64 + 16 * t + cc];
            float v1 = Wl[(kk * 32 + qq * 8 + jj * 2 + 1) * 64 + 16 * t + cc];
            u[jj] = (unsigned int)f2bf(v0) | ((unsigned int)f2bf(v1) << 16);
        }
        WB[rid] = make_uint4(u[0], u[1], u[2], u[3]);
    }
    __syncthreads();

    short8 bfr[2][4];
    #pragma unroll
    for (int kk = 0; kk < 2; ++kk)
        #pragma unroll
        for (int t = 0; t < 4; ++t) {
            F8 tmp; tmp.u = WB[(kk * 4 + t) * 64 + lane];
            bfr[kk][t] = tmp.s;
        }

    float as_[4], ad_[4];
    #pragma unroll
    for (int t = 0; t < 4; ++t) {
        as_[t] = asrc[16 * t + c];
        ad_[t] = adst[16 * t + c];
    }

    int wid = (blockIdx.x * 256 + tid) >> 6;
    int nwaves = gridDim.x * 4;

    for (int g = wid; g < NGRP; g += nwaves) {
        int base = g * 16;
        F8 a0, a1;
        a0.u = *(const uint4*)(actB + (size_t)(base + c) * HC + q * 8);
        a1.u = *(const uint4*)(actB + (size_t)(base + c) * HC + 32 + q * 8);

        floatx4 acc[4];
        #pragma unroll
        for (int t = 0; t < 4; ++t) {
            acc[t] = (floatx4){0.f, 0.f, 0.f, 0.f};
            acc[t] = __builtin_amdgcn_mfma_f32_16x16x32_bf16(a0.s, bfr[0][t], acc[t], 0, 0, 0);
            acc[t] = __builtin_amdgcn_mfma_f32_16x16x32_bf16(a1.s, bfr[1][t], acc[t], 0, 0, 0);
        }

        #pragma unroll
        for (int r = 0; r < 4; ++r) {
            float h0s = acc[0][r] * as_[0] + acc[1][r] * as_[1];
            float h1s = acc[2][r] * as_[2] + acc[3][r] * as_[3];
            float h0d = acc[0][r] * ad_[0] + acc[1][r] * ad_[1];
            float h1d = acc[2][r] * ad_[2] + acc[3][r] * ad_[3];
            #pragma unroll
            for (int off = 1; off < 16; off <<= 1) {
                h0s += __shfl_xor(h0s, off, 64);
                h1s += __shfl_xor(h1s, off, 64);
                h0d += __shfl_xor(h0d, off, 64);
                h1d += __shfl_xor(h1d, off, 64);
            }
            if (c == 0) {
                int node = base + q * 4 + r;
                *(float2*)(ssrc + node * 2) = make_float2(h0s, h1s);
                *(float2*)(sdst + node * 2) = make_float2(h0d, h1d);
            }
        }

        #pragma unroll
        for (int t = 0; t < 4; ++t)
            #pragma unroll
            for (int r = 0; r < 4; ++r)
                Cb[w][(q * 4 + r) * 64 + 16 * t + c] = f2bf(acc[t][r]);
        __builtin_amdgcn_wave_barrier();
        const uint4* cf = (const uint4*)&Cb[w][0];
        uint4* gout = (uint4*)(hcurb + (size_t)base * HC);
        gout[lane] = cf[lane];
        gout[64 + lane] = cf[64 + lane];
        __builtin_amdgcn_wave_barrier();
    }
}

// ---------------- fused edge pipeline ----------------
// One wave per dst node. Slot reduction via LDS transpose. chbuf slot
// stride = 68 floats (272 B, 16B-aligned): write bank = (sub*4+q*8+j)%32
// -> 8 accesses/bank = the b128 floor (stride 64 was 16/bank -> 1.6M
// conflicts). Reads: (4k+lane)%32 -> 2-way (free).
template <int NW, bool LAST>
__global__ void k_edge(const int* __restrict__ rowstart, const int* __restrict__ packed,
                       const float* __restrict__ ssrc, const float* __restrict__ sdst,
                       const float* __restrict__ escore_l,   // [5][2]
                       const unsigned short* __restrict__ hcurb, // [N][64] bf16
                       const float* __restrict__ eemb_l,     // [5][64]
                       const float* __restrict__ bias_l,     // [64]
                       unsigned short* __restrict__ actnext, float* __restrict__ out) {
    __shared__ float chbuf[NW][8 * CHS];  // [slot][channel] partials
    __shared__ float obuf[2][64];
    int w = threadIdx.x >> 6;
    int n = LAST ? (blockIdx.x * 4 + w) : (blockIdx.x * NW + w);
    int lane = threadIdx.x & 63;
    int sub = lane >> 3;
    int q   = lane & 7;
    int h   = q >> 2;

    int beg = rowstart[n];
    int end = rowstart[n + 1];
    float sd = sdst[n * 2 + h];

    float4 a0 = make_float4(0.f, 0.f, 0.f, 0.f);
    float4 a1 = make_float4(0.f, 0.f, 0.f, 0.f);
    float ssum = 0.f;
    for (int i = beg + sub; i < end; i += 8) {
        int p = packed[i];
        int s = p & 0x1FFFF;
        int a = (p >> 17) & 7;
        float lg = sd + ssrc[s * 2 + h] + escore_l[a * 2 + h];
        lg = lg >= 0.f ? lg : 0.2f * lg;
        float wt = __expf(lg);
        uint4 hv = *(const uint4*)(hcurb + (size_t)s * HC + q * 8);
        const float4* ep = (const float4*)(eemb_l + a * HC + q * 8);
        float4 e0 = ep[0], e1 = ep[1];
        a0.x += wt * (bf_lo(hv.x) + e0.x);
        a0.y += wt * (bf_hi(hv.x) + e0.y);
        a0.z += wt * (bf_lo(hv.y) + e0.z);
        a0.w += wt * (bf_hi(hv.y) + e0.w);
        a1.x += wt * (bf_lo(hv.z) + e1.x);
        a1.y += wt * (bf_hi(hv.z) + e1.y);
        a1.z += wt * (bf_lo(hv.w) + e1.z);
        a1.w += wt * (bf_hi(hv.w) + e1.w);
        ssum += wt;
    }
    // slot partials -> LDS (stride-68: conflict floor for b128)
    ((float4*)&chbuf[w][sub * CHS + q * 8])[0] = a0;
    ((float4*)&chbuf[w][sub * CHS + q * 8])[1] = a1;
    // ssum: 3-round butterfly, then pick head of CHANNEL `lane` (= lane>>5)
    for (int off = 8; off < 64; off <<= 1) ssum += __shfl_xor(ssum, off, 64);
    float ssum_h = __shfl(ssum, (lane >> 5) * 4, 64);
    float inv = 1.f / (ssum_h + 1e-16f);
    __builtin_amdgcn_wave_barrier();            // DS ops in-order per wave
    float s = 0.f;
    #pragma unroll
    for (int k = 0; k < 8; ++k) s += chbuf[w][k * CHS + lane];
    float v = s * inv + bias_l[lane];
    float o = v > 0.f ? v : (__expf(v) - 1.f);
    if (!LAST) {
        actnext[(size_t)n * HC + lane] = f2bf(o);
    } else {
        obuf[w][lane] = o;                      // w=0: user 4b, w=1: item 4b+1
        __syncthreads();
        if (w == 0) {
            float p = obuf[0][lane] * obuf[1][lane];
            for (int off = 32; off > 0; off >>= 1) p += __shfl_down(p, off, 64);
            if (lane == 0) out[blockIdx.x] = p;
        }
    }
}

// ---------------- launch ----------------
extern "C" void kernel_launch(void* const* d_in, const int* in_sizes, int n_in,
                              void* d_out, int out_size, void* d_ws, size_t ws_size,
                              hipStream_t stream) {
    const float* x       = (const float*)d_in[0];   // [N,4]
    const float* W0      = (const float*)d_in[1];   // [4,64]
    const float* W13     = (const float*)d_in[2];   // [3,64,64]
    const float* eemb    = (const float*)d_in[3];   // [4,5,64]
    const float* att_src = (const float*)d_in[4];   // [4,2,32]
    const float* att_dst = (const float*)d_in[5];   // [4,2,32]
    const float* bias    = (const float*)d_in[6];   // [4,64]
    const int*   eidx    = (const int*)d_in[7];     // [2,E]
    const int*   eattr   = (const int*)d_in[8];     // [E]
    float* out = (float*)d_out;

    const int* src = eidx;
    const int* dst = eidx + N_EDGES;

    char* wsb = (char*)d_ws;
    size_t off = 0;
    auto alloc = [&](size_t bytes) { char* p = wsb + off; off += (bytes + 255) & ~(size_t)255; return p; };
    unsigned short* hcurb  = (unsigned short*)alloc((size_t)N_NODES * HC * 2);
    unsigned short* actB   = (unsigned short*)alloc((size_t)N_NODES * HC * 2);
    float*          ssrc   = (float*)alloc((size_t)N_NODES * 2 * 4);
    float*          sdst   = (float*)alloc((size_t)N_NODES * 2 * 4);
    float*          escore = (float*)alloc(NLAYERS * ECLS * NHEADS * 4);
    int*            bh     = (int*)alloc((size_t)NBUCK * NBLK * 4);
    int*            bbase  = (int*)alloc((size_t)NBUCK * NBLK * 4);
    int*            part   = (int*)alloc(256 * 4);
    int*            rowstart = (int*)alloc(((size_t)N_NODES + 1) * 4);
    int*            bkt    = (int*)alloc((size_t)N_EDGES * 4);
    int*            packed = (int*)alloc((size_t)N_EDGES * 4);

    // ---- CSR build P1 + layer-0 linear + escore (merged) ----
    k_chist_lin0<<<NBLK + LIN0_BLOCKS + 1, 256, 0, stream>>>(
        dst, bh, x, W0, att_src, att_dst, hcurb, ssrc, sdst, eemb, escore);
    k_s1<<<NBUCK, NBLK, 0, stream>>>(bh, bbase, part);
    k_cscatter<<<NBLK, 256, 0, stream>>>(src, dst, eattr, bbase, part, bkt);
    k_fine<<<NBUCK, 512, 0, stream>>>(part, bkt, packed, rowstart);

    for (int l = 0; l < NLAYERS; ++l) {
        if (l > 0) {
            k_linmfma<<<512, 256, 0, stream>>>(
                actB, W13 + (size_t)(l - 1) * HC * HC,
                att_src + l * HC, att_dst + l * HC, hcurb, ssrc, sdst);
        }
        const float* esl = escore + l * ECLS * NHEADS;
        const float* el  = eemb + (size_t)l * ECLS * HC;
        const float* bl  = bias + l * HC;
        if (l < NLAYERS - 1)
            k_edge<1, false><<<N_NODES, 64, 0, stream>>>(
                rowstart, packed, ssrc, sdst, esl, hcurb, el, bl, actB, nullptr);
        else
            k_edge<2, true><<<N_NODES / 4, 128, 0, stream>>>(
                rowstart, packed, ssrc, sdst, esl, hcurb, el, bl, nullptr, out);
    }
}